// Round 10
// baseline (848.346 us; speedup 1.0000x reference)
//
#include <hip/hip_runtime.h>
#include <hip/hip_bf16.h>

#define HEADS 8
#define DH 64
#define EMB 512
#define NP 4352
#define NTOK 4097
#define PADF 255
#define LM 256
#define SCALE 0.125f

typedef __attribute__((ext_vector_type(8))) short bf8;
typedef __attribute__((ext_vector_type(4))) float f4;
typedef __attribute__((ext_vector_type(8))) unsigned short us8;
typedef __attribute__((ext_vector_type(4))) unsigned short us4;
typedef unsigned short u16;

__device__ __forceinline__ u16 f2b(float f){
  union { float f; unsigned u; } x; x.f = f;
  unsigned r = x.u + 0x7fffu + ((x.u>>16)&1u);
  return (u16)(r>>16);
}
__device__ __forceinline__ float b2f(u16 h){
  union { unsigned u; float f; } x; x.u = ((unsigned)h)<<16;
  return x.f;
}

__device__ __forceinline__ void gload_lds(const u16* g, u16* l){
  __builtin_amdgcn_global_load_lds((const __attribute__((address_space(1))) void*)g,
                                   (__attribute__((address_space(3))) void*)l, 16, 0, 0);
}

// counted-vmcnt pipeline helpers: wait for the OLDEST tile's loads only.
#define WAITCNT(N) asm volatile("s_waitcnt vmcnt(" #N ")" ::: "memory")
#define SCHED_FENCE() __builtin_amdgcn_sched_barrier(0)
#define BARRIER() __builtin_amdgcn_s_barrier()

// ======== 128x128 NT bf16 GEMM, BK=32, depth-3 counted-vmcnt pipeline ========
// MODE 0: fp32 store; MODE 2: bf16 store; MODE 3: fp32 C[gm-rowoff] += v;
// MODE 4: fp32 atomicAdd to C[gm-rowoff] (split-K safe; bias only on kc==0)
template<int MODE>
__global__ __launch_bounds__(256)
void k_g128(const u16* __restrict__ A, const u16* __restrict__ B,
            float* __restrict__ C, u16* __restrict__ C16,
            int K, int lda, int ldb, int ldc,
            long sAb, long sAh, long sBb, long sBh, long sCb, long sCh, int nh,
            float alpha, const float* __restrict__ bias, int relu, int rowoff,
            int nx, int ksplit)
{
  int z = blockIdx.z;
  const u16* Ab = A + (long)(z/nh)*sAb + (long)(z%nh)*sAh;
  const u16* Bb = B + (long)(z/nh)*sBb + (long)(z%nh)*sBh;
  long cb = (long)(z/nh)*sCb + (long)(z%nh)*sCh;
  int bx = blockIdx.x % nx, kc = blockIdx.x / nx;
  int m0 = blockIdx.y*128, n0 = bx*128;
  int klen = K/ksplit, kbeg = kc*klen, nch = klen/32;
  __shared__ u16 As[3][4096];
  __shared__ u16 Bs[3][4096];
  int tid=threadIdx.x, w=tid>>6, lane=tid&63, q=lane>>4, lr=lane&15;
  int wrow=(w>>1)*64, wcol=(w&1)*64;
  int srow = tid>>2, scol = (tid&3)*8;
  const u16* ga  = Ab + (long)(m0+srow)*lda + kbeg + scol;
  const u16* ga2 = Ab + (long)(m0+64+srow)*lda + kbeg + scol;
  const u16* gb  = Bb + (long)(n0+srow)*ldb + kbeg + scol;
  const u16* gb2 = Bb + (long)(n0+64+srow)*ldb + kbeg + scol;
  int lo = srow*32 + scol;
  f4 acc[4][4] = {};
  auto stage = [&](int r, int c){
    gload_lds(ga  + c*32, &As[r][lo]);
    gload_lds(ga2 + c*32, &As[r][2048+lo]);
    gload_lds(gb  + c*32, &Bs[r][lo]);
    gload_lds(gb2 + c*32, &Bs[r][2048+lo]);
  };
  auto compute = [&](int r){
    bf8 af[4], bfr[4];
    #pragma unroll
    for(int rr=0;rr<4;rr++) af[rr]  = *(const bf8*)&As[r][(wrow + rr*16 + lr)*32 + q*8];
    #pragma unroll
    for(int t=0;t<4;t++) bfr[t] = *(const bf8*)&Bs[r][(wcol + t*16 + lr)*32 + q*8];
    #pragma unroll
    for(int rr=0;rr<4;rr++)
      #pragma unroll
      for(int t=0;t<4;t++)
        acc[rr][t] = __builtin_amdgcn_mfma_f32_16x16x32_bf16(af[rr], bfr[t], acc[rr][t], 0,0,0);
  };
  stage(0,0);
  if(nch>1) stage(1,1);
  if(nch>2) stage(2,2);
  int bufc = 0;
  for(int c=0;c<nch;c++){
    int rem = nch-1-c;
    if(rem>=2) WAITCNT(8); else if(rem==1) WAITCNT(4); else WAITCNT(0);
    SCHED_FENCE();
    BARRIER();
    compute(bufc);
    SCHED_FENCE();
    BARRIER();
    SCHED_FENCE();
    if(c+3<nch) stage(bufc, c+3);
    bufc = (bufc+1==3)?0:bufc+1;
  }
  #pragma unroll
  for(int r=0;r<4;r++){
    #pragma unroll
    for(int t=0;t<4;t++){
      #pragma unroll
      for(int e=0;e<4;e++){
        int gm = m0 + wrow + r*16 + q*4 + e;
        int gn = n0 + wcol + t*16 + lr;
        float v = acc[r][t][e]*alpha;
        if(MODE==4){
          if(bias && kc==0) v += bias[gn];
          if(gm>=rowoff) atomicAdd(&C[cb + (long)(gm-rowoff)*ldc + gn], v);
        } else {
          if(bias) v += bias[gn];
          if(relu) v = fmaxf(v,0.f);
          if(MODE==0) C[cb + (long)gm*ldc + gn] = v;
          else if(MODE==2) C16[cb + (long)gm*ldc + gn] = f2b(v);
          else { if(gm>=rowoff) C[cb + (long)(gm-rowoff)*ldc + gn] += v; }
        }
      }
    }
  }
}

// ======== 64x64 NT bf16 GEMM, 4-buffer single-barrier counted-vmcnt pipeline ====
// stage at iter c targets buf (c+3)&3 = buffer computed at iter c-1; the single
// barrier at top of iter c guarantees all waves finished that compute.
// MODE 0: fp32 store; MODE 2: bf16 store; MODE 3: fp32 atomicAdd
// MODE 5: fp32 C[gm-rowoff] += v + bias; MODE 6: fp32 C = relu(v + bias)
template<int MODE>
__global__ __launch_bounds__(256)
void k_g64(const u16* __restrict__ A, const u16* __restrict__ B,
           float* __restrict__ C, u16* __restrict__ C16,
           int K, int lda, int ldb, int ldc,
           long sAb, long sAh, long sBb, long sBh, long sCb, long sCh, int nh,
           float alpha, const float* __restrict__ bias, int rowoff, int moff,
           int nx, int ksplit)
{
  int z = blockIdx.z;
  const u16* Ab = A + (long)(z/nh)*sAb + (long)(z%nh)*sAh;
  const u16* Bb = B + (long)(z/nh)*sBb + (long)(z%nh)*sBh;
  long cb = (long)(z/nh)*sCb + (long)(z%nh)*sCh;
  int bx = blockIdx.x % nx, kc = blockIdx.x / nx;
  int m0 = blockIdx.y*64 + moff, n0 = bx*64;
  int klen = K/ksplit, kbeg = kc*klen, nch = klen/32;
  __shared__ u16 As[4][2048];
  __shared__ u16 Bs[4][2048];
  int tid=threadIdx.x, w=tid>>6, lane=tid&63, q=lane>>4, lr=lane&15;
  int srow = tid>>2, scol = (tid&3)*8;
  const u16* ga = Ab + (long)(m0+srow)*lda + kbeg + scol;
  const u16* gb = Bb + (long)(n0+srow)*ldb + kbeg + scol;
  int lo = srow*32 + scol;
  f4 acc[4] = {};
  auto stage = [&](int r, int c){
    gload_lds(ga + c*32, &As[r][lo]);
    gload_lds(gb + c*32, &Bs[r][lo]);
  };
  auto compute = [&](int r){
    bf8 af = *(const bf8*)&As[r][(w*16 + lr)*32 + q*8];
    #pragma unroll
    for(int t=0;t<4;t++){
      bf8 bfr = *(const bf8*)&Bs[r][(t*16 + lr)*32 + q*8];
      acc[t] = __builtin_amdgcn_mfma_f32_16x16x32_bf16(af, bfr, acc[t], 0,0,0);
    }
  };
  stage(0,0);
  if(nch>1) stage(1,1);
  if(nch>2) stage(2,2);
  for(int c=0;c<nch;c++){
    int rem = nch-1-c;
    if(rem>=2) WAITCNT(4); else if(rem==1) WAITCNT(2); else WAITCNT(0);
    SCHED_FENCE();
    BARRIER();
    SCHED_FENCE();
    if(c+3<nch) stage((c+3)&3, c+3);
    compute(c&3);
    SCHED_FENCE();
  }
  #pragma unroll
  for(int t=0;t<4;t++){
    #pragma unroll
    for(int e=0;e<4;e++){
      int gm = m0 + w*16 + q*4 + e;
      int gn = n0 + t*16 + lr;
      float v = acc[t][e]*alpha;
      if(MODE==0) C[cb + (long)gm*ldc + gn] = v;
      else if(MODE==2) C16[cb + (long)gm*ldc + gn] = f2b(v);
      else if(MODE==3) atomicAdd(&C[cb + (long)gm*ldc + gn], v);
      else if(MODE==5){
        v += bias[gn];
        if(gm>=rowoff) C[cb + (long)(gm-rowoff)*ldc + gn] += v;
      }
      else if(MODE==6){
        v = fmaxf(v + bias[gn], 0.f);
        C[cb + (long)gm*ldc + gn] = v;
      }
    }
  }
}

// ======== pinv GEMM on bf16 hi/lo pairs — 32x64 strips, 4-buffer 1-barrier ======
__global__ __launch_bounds__(256)
void k_pg3(const u16* __restrict__ Ah, const u16* __restrict__ Al,
           const u16* __restrict__ Bh, const u16* __restrict__ Bl,
           u16* __restrict__ Oh, u16* __restrict__ Ol, float na, float nd,
           u16* __restrict__ TOh, u16* __restrict__ TOl, float ta, float td)
{
  long zo = (long)blockIdx.z*65536;
  int m0 = blockIdx.y*32, n0 = blockIdx.x*64;
  __shared__ u16 S[4][6144];
  int tid=threadIdx.x, w=tid>>6, lane=tid&63, q=lane>>4, lr=lane&15;
  int t2 = tid & 127;
  const u16* srcA = (tid<128 ? Ah : Al) + zo + (long)(m0 + (t2>>2))*256 + (t2&3)*8;
  const u16* srcBh = Bh + zo + (long)(n0 + (tid>>2))*256 + (tid&3)*8;
  const u16* srcBl = Bl + zo + (long)(n0 + (tid>>2))*256 + (tid&3)*8;
  f4 acc[2] = {};
  auto stage = [&](int r, int c){
    gload_lds(srcA  + c*32, &S[r][tid*8]);
    gload_lds(srcBh + c*32, &S[r][2048 + tid*8]);
    gload_lds(srcBl + c*32, &S[r][4096 + tid*8]);
  };
  int mrow = (w>>1)*16 + lr;
  auto compute = [&](int r){
    bf8 ah = *(const bf8*)&S[r][mrow*32 + q*8];
    bf8 al = *(const bf8*)&S[r][1024 + mrow*32 + q*8];
    #pragma unroll
    for(int t=0;t<2;t++){
      int nrow = (w&1)*32 + t*16 + lr;
      bf8 bh = *(const bf8*)&S[r][2048 + nrow*32 + q*8];
      bf8 bl = *(const bf8*)&S[r][4096 + nrow*32 + q*8];
      acc[t] = __builtin_amdgcn_mfma_f32_16x16x32_bf16(ah, bh, acc[t], 0,0,0);
      acc[t] = __builtin_amdgcn_mfma_f32_16x16x32_bf16(ah, bl, acc[t], 0,0,0);
      acc[t] = __builtin_amdgcn_mfma_f32_16x16x32_bf16(al, bh, acc[t], 0,0,0);
    }
  };
  stage(0,0);
  stage(1,1);
  stage(2,2);
  for(int c=0;c<8;c++){
    int rem = 7-c;
    if(rem>=2) WAITCNT(6); else if(rem==1) WAITCNT(3); else WAITCNT(0);
    SCHED_FENCE();
    BARRIER();
    SCHED_FENCE();
    if(c+3<8) stage((c+3)&3, c+3);
    compute(c&3);
    SCHED_FENCE();
  }
  #pragma unroll
  for(int t=0;t<2;t++){
    int gn = n0 + (w&1)*32 + t*16 + lr;
    if(Oh){
      #pragma unroll
      for(int r=0;r<4;r++){
        int gm = m0 + (w>>1)*16 + q*4 + r;
        float v = na*acc[t][r] + ((gm==gn)?nd:0.f);
        u16 h = f2b(v);
        long o = zo + (long)gm*256 + gn;
        Oh[o] = h; Ol[o] = f2b(v - b2f(h));
      }
    }
    if(TOh){
      us4 th, tl;
      #pragma unroll
      for(int r=0;r<4;r++){
        int gm = m0 + (w>>1)*16 + q*4 + r;
        float v = ta*acc[t][r] + ((gm==gn)?td:0.f);
        u16 h = f2b(v);
        th[r] = h; tl[r] = f2b(v - b2f(h));
      }
      long o = zo + (long)gn*256 + (m0 + (w>>1)*16 + q*4);
      *(us4*)&TOh[o] = th; *(us4*)&TOl[o] = tl;
    }
  }
}

// ======== dual-A pinv GEMM (4-buffer 1-barrier): half grid z_new=0.25*Z@V,
// half y_new=0.25*P@V (+ T_new = 7I - y_new transposed). grid (4,16,16). ========
__global__ __launch_bounds__(256)
void k_pg3b(const u16* __restrict__ Zh, const u16* __restrict__ Zl,
            const u16* __restrict__ Ph, const u16* __restrict__ Pl,
            const u16* __restrict__ Bh, const u16* __restrict__ Bl,
            u16* __restrict__ Ozh, u16* __restrict__ Ozl,
            u16* __restrict__ Oyh, u16* __restrict__ Oyl,
            u16* __restrict__ Tyh, u16* __restrict__ Tyl)
{
  long zo = (long)blockIdx.z*65536;
  int ysel = blockIdx.y>>3;
  int m0 = (blockIdx.y&7)*32, n0 = blockIdx.x*64;
  const u16* Ah = ysel ? Ph : Zh;
  const u16* Al = ysel ? Pl : Zl;
  __shared__ u16 S[4][6144];
  int tid=threadIdx.x, w=tid>>6, lane=tid&63, q=lane>>4, lr=lane&15;
  int t2 = tid & 127;
  const u16* srcA = (tid<128 ? Ah : Al) + zo + (long)(m0 + (t2>>2))*256 + (t2&3)*8;
  const u16* srcBh = Bh + zo + (long)(n0 + (tid>>2))*256 + (tid&3)*8;
  const u16* srcBl = Bl + zo + (long)(n0 + (tid>>2))*256 + (tid&3)*8;
  f4 acc[2] = {};
  auto stage = [&](int r, int c){
    gload_lds(srcA  + c*32, &S[r][tid*8]);
    gload_lds(srcBh + c*32, &S[r][2048 + tid*8]);
    gload_lds(srcBl + c*32, &S[r][4096 + tid*8]);
  };
  int mrow = (w>>1)*16 + lr;
  auto compute = [&](int r){
    bf8 ah = *(const bf8*)&S[r][mrow*32 + q*8];
    bf8 al = *(const bf8*)&S[r][1024 + mrow*32 + q*8];
    #pragma unroll
    for(int t=0;t<2;t++){
      int nrow = (w&1)*32 + t*16 + lr;
      bf8 bh = *(const bf8*)&S[r][2048 + nrow*32 + q*8];
      bf8 bl = *(const bf8*)&S[r][4096 + nrow*32 + q*8];
      acc[t] = __builtin_amdgcn_mfma_f32_16x16x32_bf16(ah, bh, acc[t], 0,0,0);
      acc[t] = __builtin_amdgcn_mfma_f32_16x16x32_bf16(ah, bl, acc[t], 0,0,0);
      acc[t] = __builtin_amdgcn_mfma_f32_16x16x32_bf16(al, bh, acc[t], 0,0,0);
    }
  };
  stage(0,0);
  stage(1,1);
  stage(2,2);
  for(int c=0;c<8;c++){
    int rem = 7-c;
    if(rem>=2) WAITCNT(6); else if(rem==1) WAITCNT(3); else WAITCNT(0);
    SCHED_FENCE();
    BARRIER();
    SCHED_FENCE();
    if(c+3<8) stage((c+3)&3, c+3);
    compute(c&3);
    SCHED_FENCE();
  }
  #pragma unroll
  for(int t=0;t<2;t++){
    int gn = n0 + (w&1)*32 + t*16 + lr;
    if(!ysel){
      #pragma unroll
      for(int r=0;r<4;r++){
        int gm = m0 + (w>>1)*16 + q*4 + r;
        float v = 0.25f*acc[t][r];
        u16 h = f2b(v);
        long o = zo + (long)gm*256 + gn;
        Ozh[o] = h; Ozl[o] = f2b(v - b2f(h));
      }
    } else {
      us4 th, tl;
      #pragma unroll
      for(int r=0;r<4;r++){
        int gm = m0 + (w>>1)*16 + q*4 + r;
        float v = 0.25f*acc[t][r];
        u16 h = f2b(v);
        long o = zo + (long)gm*256 + gn;
        Oyh[o] = h; Oyl[o] = f2b(v - b2f(h));
        float tv = -v + ((gm==gn)?7.f:0.f);
        u16 h2 = f2b(tv);
        th[r] = h2; tl[r] = f2b(tv - b2f(h2));
      }
      long o = zo + (long)gn*256 + (m0 + (w>>1)*16 + q*4);
      *(us4*)&Tyh[o] = th; *(us4*)&Tyl[o] = tl;
    }
  }
}

// ======== fused attn2: S=q_l@k_l^T; P=softmax(S) -> att2 fp32; colsum atomicAdd ===
__global__ __launch_bounds__(256)
void k_att2f(const u16* __restrict__ ql, const u16* __restrict__ kl,
             float* __restrict__ att2, float* __restrict__ colsum)
{
  int z = blockIdx.y;
  int m0 = blockIdx.x*64;
  __shared__ u16 SQ[64*64];
  __shared__ u16 SKL[256*64];
  int tid=threadIdx.x, w=tid>>6, lane=tid&63, q=lane>>4, lr=lane&15;
  {
    const u16* qb = ql + (long)z*16384 + m0*64;
    #pragma unroll
    for(int p=0;p<2;p++){
      int idx = tid + p*256; int row = idx>>3; int js = ((idx&7)^(row&7))<<3;
      gload_lds(qb + row*64 + js, &SQ[idx*8]);
    }
    const u16* kb = kl + (long)z*16384;
    #pragma unroll
    for(int p=0;p<8;p++){
      int idx = tid + p*256; int row = idx>>3; int js = ((idx&7)^(row&7))<<3;
      gload_lds(kb + row*64 + js, &SKL[idx*8]);
    }
  }
  __syncthreads();
  f4 acc[16] = {};
  {
    int ar = w*16+lr;
    bf8 af0 = *(const bf8*)&SQ[ar*64 + ((q^(ar&7))<<3)];
    bf8 af1 = *(const bf8*)&SQ[ar*64 + (((q|4)^(ar&7))<<3)];
    #pragma unroll
    for(int t=0;t<16;t++){
      int br = t*16+lr;
      bf8 b0 = *(const bf8*)&SKL[br*64 + ((q^(br&7))<<3)];
      bf8 b1 = *(const bf8*)&SKL[br*64 + (((q|4)^(br&7))<<3)];
      acc[t] = __builtin_amdgcn_mfma_f32_16x16x32_bf16(af0, b0, acc[t], 0,0,0);
      acc[t] = __builtin_amdgcn_mfma_f32_16x16x32_bf16(af1, b1, acc[t], 0,0,0);
    }
  }
  float mx[4] = {-1e30f,-1e30f,-1e30f,-1e30f};
  #pragma unroll
  for(int t=0;t<16;t++)
    #pragma unroll
    for(int e=0;e<4;e++) mx[e] = fmaxf(mx[e], acc[t][e]);
  #pragma unroll
  for(int s=1;s<16;s<<=1)
    #pragma unroll
    for(int e=0;e<4;e++) mx[e] = fmaxf(mx[e], __shfl_xor(mx[e], s));
  float sm[4] = {0.f,0.f,0.f,0.f};
  #pragma unroll
  for(int t=0;t<16;t++)
    #pragma unroll
    for(int e=0;e<4;e++){ float p = expf(acc[t][e] - mx[e]); acc[t][e]=p; sm[e]+=p; }
  #pragma unroll
  for(int s=1;s<16;s<<=1)
    #pragma unroll
    for(int e=0;e<4;e++) sm[e] += __shfl_xor(sm[e], s);
  float inv[4];
  #pragma unroll
  for(int e=0;e<4;e++) inv[e] = 1.f/sm[e];
  float* ab = att2 + (long)z*65536;
  #pragma unroll
  for(int t=0;t<16;t++){
    float cs = 0.f;
    #pragma unroll
    for(int e=0;e<4;e++){
      float p = acc[t][e]*inv[e];
      ab[(long)(m0 + w*16 + q*4 + e)*256 + t*16 + lr] = p;
      cs += p;
    }
    cs += __shfl_xor(cs, 16);
    cs += __shfl_xor(cs, 32);
    if(q==0) atomicAdd(&colsum[z*256 + t*16 + lr], cs);
  }
}

// ======== fused attn3@v flash: partial softmax(q_l@k^T)@v over 256-token chunks ===
__global__ __launch_bounds__(256)
void k_att3(const u16* __restrict__ qkv16, const u16* __restrict__ ql,
            const u16* __restrict__ vT, float* __restrict__ partO,
            float* __restrict__ pm, float* __restrict__ pl)
{
  int kc = blockIdx.x, jt = blockIdx.y, z = blockIdx.z;
  int b = z>>3, h = z&7;
  __shared__ u16 SQ[64*64];
  __shared__ u16 SK[2][64*64];
  __shared__ u16 SV[2][64*64];
  __shared__ u16 SP[64*64];
  int tid=threadIdx.x, w=tid>>6, lane=tid&63, q=lane>>4, lr=lane&15;
  const u16* kb = qkv16 + (long)b*NP*1536 + 512 + h*64;
  const u16* vb = vT + (long)z*64*NP;
  int t00 = kc*256;
  {
    const u16* qb = ql + (long)z*16384 + jt*64*64;
    #pragma unroll
    for(int p=0;p<2;p++){
      int idx = tid + p*256; int row = idx>>3; int js = ((idx&7)^(row&7))<<3;
      gload_lds(qb + row*64 + js, &SQ[idx*8]);
    }
  }
  auto stageKV = [&](int r, int i){
    int t0 = t00 + i*64;
    #pragma unroll
    for(int p=0;p<2;p++){
      int idx = tid + p*256; int row = idx>>3; int js = ((idx&7)^(row&7))<<3;
      gload_lds(kb + (long)(t0+row)*1536 + js, &SK[r][idx*8]);
      gload_lds(vb + (long)row*NP + t0 + js, &SV[r][idx*8]);
    }
  };
  stageKV(0,0);
  __syncthreads();
  int ar = w*16+lr;
  bf8 af0 = *(const bf8*)&SQ[ar*64 + ((q^(ar&7))<<3)];
  bf8 af1 = *(const bf8*)&SQ[ar*64 + (((q|4)^(ar&7))<<3)];
  f4 o[4] = {};
  float m[4] = {-3e38f,-3e38f,-3e38f,-3e38f};
  float l[4] = {0.f,0.f,0.f,0.f};
  for(int i=0;i<4;i++){
    int cur = i&1;
    if(i<3) stageKV(cur^1, i+1);
    f4 s[4] = {};
    #pragma unroll
    for(int t=0;t<4;t++){
      int br = t*16+lr;
      bf8 b0 = *(const bf8*)&SK[cur][br*64 + ((q^(br&7))<<3)];
      bf8 b1 = *(const bf8*)&SK[cur][br*64 + (((q|4)^(br&7))<<3)];
      s[t] = __builtin_amdgcn_mfma_f32_16x16x32_bf16(af0, b0, s[t], 0,0,0);
      s[t] = __builtin_amdgcn_mfma_f32_16x16x32_bf16(af1, b1, s[t], 0,0,0);
    }
    float tm[4];
    #pragma unroll
    for(int e=0;e<4;e++) tm[e] = fmaxf(fmaxf(s[0][e],s[1][e]), fmaxf(s[2][e],s[3][e]));
    #pragma unroll
    for(int sh=1; sh<16; sh<<=1)
      #pragma unroll
      for(int e=0;e<4;e++) tm[e] = fmaxf(tm[e], __shfl_xor(tm[e], sh));
    float rs[4];
    #pragma unroll
    for(int e=0;e<4;e++){
      float mn = fmaxf(m[e], tm[e]);
      float sc = expf(m[e]-mn);
      m[e] = mn;
      l[e] *= sc;
      rs[e] = 0.f;
      o[0][e]*=sc; o[1][e]*=sc; o[2][e]*=sc; o[3][e]*=sc;
    }
    #pragma unroll
    for(int t=0;t<4;t++)
      #pragma unroll
      for(int e=0;e<4;e++){
        float p = expf(s[t][e]-m[e]);
        rs[e] += p;
        int prow = w*16+q*4+e, pcol = t*16+lr;
        SP[prow*64 + (((pcol>>3)^(prow&7))<<3) + (pcol&7)] = f2b(p);
      }
    #pragma unroll
    for(int sh=1; sh<16; sh<<=1)
      #pragma unroll
      for(int e=0;e<4;e++) rs[e] += __shfl_xor(rs[e], sh);
    #pragma unroll
    for(int e=0;e<4;e++) l[e] += rs[e];
    int pr = w*16+lr;
    #pragma unroll
    for(int ks=0;ks<2;ks++){
      bf8 pa = *(const bf8*)&SP[pr*64 + (((ks*4+q)^(pr&7))<<3)];
      #pragma unroll
      for(int t2=0;t2<4;t2++){
        int rr = t2*16+lr;
        bf8 vv = *(const bf8*)&SV[cur][rr*64 + (((ks*4+q)^(rr&7))<<3)];
        o[t2] = __builtin_amdgcn_mfma_f32_16x16x32_bf16(pa, vv, o[t2], 0,0,0);
      }
    }
    __syncthreads();
  }
  long pb = (long)(z*17+kc)*256 + jt*64 + w*16;
  #pragma unroll
  for(int e=0;e<4;e++){
    int jg = q*4+e;
    #pragma unroll
    for(int t2=0;t2<4;t2++)
      partO[(pb + jg)*64 + t2*16 + lr] = o[t2][e];
    if(lr==0){ pm[pb + jg] = m[e]; pl[pb + jg] = l[e]; }
  }
}

// merge 17 kc-partials -> avbT16[z][d][j] (bf16, transposed). grid (16 jq, 16 z), 128 thr.
__global__ __launch_bounds__(128)
void k_mrg3(const float* __restrict__ partO, const float* __restrict__ pm,
            const float* __restrict__ pl, u16* __restrict__ avbT16)
{
  int jq = blockIdx.x, z = blockIdx.y, tid = threadIdx.x;
  int j0 = jq*16;
  __shared__ float wk[16][17];
  __shared__ u16 T[16][72];
  if(tid < 16){
    int j = j0 + tid;
    float mm[17];
    float M = -3e38f;
    #pragma unroll
    for(int kc=0;kc<17;kc++){ mm[kc]=pm[(z*17+kc)*256 + j]; M=fmaxf(M,mm[kc]); }
    float s = 0.f;
    #pragma unroll
    for(int kc=0;kc<17;kc++){ float e=expf(mm[kc]-M); wk[tid][kc]=e; s+=e*pl[(z*17+kc)*256 + j]; }
    float inv = 1.f/s;
    #pragma unroll
    for(int kc=0;kc<17;kc++) wk[tid][kc]*=inv;
  }
  __syncthreads();
  float acc[8];
  #pragma unroll
  for(int p=0;p<8;p++) acc[p]=0.f;
  for(int kc=0;kc<17;kc++){
    long base = ((long)(z*17+kc)*256 + j0)*64;
    #pragma unroll
    for(int p=0;p<8;p++){
      int idx = tid + p*128;
      acc[p] += wk[idx>>6][kc]*partO[base + idx];
    }
  }
  #pragma unroll
  for(int p=0;p<8;p++){ int idx = tid + p*128; T[idx>>6][idx&63] = f2b(acc[p]); }
  __syncthreads();
  int d = tid>>1, jh = (tid&1)*8;
  us8 vv;
  #pragma unroll
  for(int u=0;u<8;u++) vv[u] = T[jh+u][d];
  *(us8*)&avbT16[(long)(z*64+d)*256 + j0 + jh] = vv;
}

// ======== fused attn1 + res-conv: S=SCALE*q@kl^T; P=softmax(S); O=P@zav;
// Qo16 = bf16(O + dwconv33(v)). LDS XOR-swizzled; conv phase reuses SKL/SZV. ====
__global__ __launch_bounds__(256)
void k_att1(const u16* __restrict__ qkv16, const u16* __restrict__ kl,
            const u16* __restrict__ zavT, const float* __restrict__ resk,
            u16* __restrict__ Qo16)
{
  int z = blockIdx.y, b = z>>3, h = z&7;
  int m0 = blockIdx.x*64;
  __shared__ u16 SQ[64*64];
  __shared__ u16 SKL[256*64];
  __shared__ u16 SZV[64*256];
  int tid=threadIdx.x, w=tid>>6, lane=tid&63, q=lane>>4, lr=lane&15;
  {
    const u16* qb = qkv16 + (long)b*NP*1536 + h*64;
    #pragma unroll
    for(int p=0;p<2;p++){
      int idx = tid + p*256; int row = idx>>3; int js = ((idx&7)^(row&7))<<3;
      gload_lds(qb + (long)(m0+row)*1536 + js, &SQ[idx*8]);
    }
    const u16* kb = kl + (long)z*16384;
    #pragma unroll
    for(int p=0;p<8;p++){
      int idx = tid + p*256; int row = idx>>3; int js = ((idx&7)^(row&7))<<3;
      gload_lds(kb + row*64 + js, &SKL[idx*8]);
    }
    const u16* zb = zavT + (long)z*16384;
    #pragma unroll
    for(int p=0;p<8;p++){
      int idx = tid + p*256; int row = idx>>5; int cs = ((idx&31)^(row&7))<<3;
      gload_lds(zb + row*256 + cs, &SZV[idx*8]);
    }
  }
  __syncthreads();
  f4 acc[16] = {};
  {
    int ar = w*16+lr;
    bf8 af0 = *(const bf8*)&SQ[ar*64 + ((q^(ar&7))<<3)];
    bf8 af1 = *(const bf8*)&SQ[ar*64 + (((q|4)^(ar&7))<<3)];
    #pragma unroll
    for(int t=0;t<16;t++){
      int br = t*16+lr;
      bf8 b0 = *(const bf8*)&SKL[br*64 + ((q^(br&7))<<3)];
      bf8 b1 = *(const bf8*)&SKL[br*64 + (((q|4)^(br&7))<<3)];
      acc[t] = __builtin_amdgcn_mfma_f32_16x16x32_bf16(af0, b0, acc[t], 0,0,0);
      acc[t] = __builtin_amdgcn_mfma_f32_16x16x32_bf16(af1, b1, acc[t], 0,0,0);
    }
  }
  float mx[4] = {-1e30f,-1e30f,-1e30f,-1e30f};
  #pragma unroll
  for(int t=0;t<16;t++)
    #pragma unroll
    for(int e=0;e<4;e++) mx[e] = fmaxf(mx[e], acc[t][e]*SCALE);
  #pragma unroll
  for(int s=1;s<16;s<<=1)
    #pragma unroll
    for(int e=0;e<4;e++) mx[e] = fmaxf(mx[e], __shfl_xor(mx[e], s));
  float sm[4] = {0.f,0.f,0.f,0.f};
  #pragma unroll
  for(int t=0;t<16;t++)
    #pragma unroll
    for(int e=0;e<4;e++){ float p = expf(acc[t][e]*SCALE - mx[e]); acc[t][e]=p; sm[e]+=p; }
  #pragma unroll
  for(int s=1;s<16;s<<=1)
    #pragma unroll
    for(int e=0;e<4;e++) sm[e] += __shfl_xor(sm[e], s);
  float inv[4];
  #pragma unroll
  for(int e=0;e<4;e++) inv[e] = 1.f/sm[e];
  __syncthreads();
  u16* PS = SKL;   // reuse as 64 rows x 256 cols, swizzled
  #pragma unroll
  for(int t=0;t<16;t++)
    #pragma unroll
    for(int e=0;e<4;e++){
      int prow = w*16 + q*4 + e, pcol = t*16 + lr;
      PS[prow*256 + (((pcol>>3)^(prow&7))<<3) + (pcol&7)] = f2b(acc[t][e]*inv[e]);
    }
  __syncthreads();
  f4 acc2[4] = {};
  int pr = w*16+lr;
  #pragma unroll
  for(int ks=0;ks<8;ks++){
    bf8 af = *(const bf8*)&PS[pr*256 + (((ks*4+q)^(pr&7))<<3)];
    #pragma unroll
    for(int t=0;t<4;t++){
      int rr = t*16+lr;
      bf8 bf_ = *(const bf8*)&SZV[rr*256 + (((ks*4+q)^(rr&7))<<3)];
      acc2[t] = __builtin_amdgcn_mfma_f32_16x16x32_bf16(af, bf_, acc2[t], 0,0,0);
    }
  }
  // ---- fused res-conv epilogue ----
  __syncthreads();                       // all PS/SZV reads done; safe to reuse
  float* PO  = (float*)SZV;              // 64 x 68 fp32
  float* SVW = (float*)SKL;              // 96 x 64 fp32
  #pragma unroll
  for(int t=0;t<4;t++)
    #pragma unroll
    for(int r=0;r<4;r++)
      PO[(w*16 + q*4 + r)*68 + t*16 + lr] = acc2[t][r];
  {
    const u16* vb = qkv16 + (long)b*NP*1536 + 1024 + h*64;
    #pragma unroll
    for(int s=0;s<3;s++){
      int idx = tid + s*256;
      int row = idx>>3, c8 = (idx&7)*8;
      int p = m0 - 16 + row;
      if(p>=0 && p<NP){
        us8 v = *(const us8*)&vb[(long)p*1536 + c8];
        #pragma unroll
        for(int jj=0;jj<8;jj++) SVW[row*64+c8+jj] = b2f(v[jj]);
      } else {
        #pragma unroll
        for(int jj=0;jj<8;jj++) SVW[row*64+c8+jj] = 0.f;
      }
    }
  }
  __syncthreads();
  int d = tid&63, lt = (tid>>6)*16;
  float acc3[16] = {};
  #pragma unroll
  for(int s=0;s<48;s++){
    float val = SVW[(lt+s)*64 + d];
    #pragma unroll
    for(int j=0;j<16;j++){
      int tap = s - j;
      if(tap>=0 && tap<33) acc3[j] += resk[h*33+tap]*val;
    }
  }
  #pragma unroll
  for(int j=0;j<16;j++){
    long idx = ((long)b*NP + m0 + lt + j)*EMB + h*64 + d;
    Qo16[idx] = f2b(PO[(lt+j)*68 + d] + acc3[j]);
  }
}

// weight transpose+convert: in fp32 [K][N] -> out bf16 [N][K]
__global__ void k_wT(const float* __restrict__ in, u16* __restrict__ out, int K, int N){
  int n0=blockIdx.x*32, k0=blockIdx.y*32, tid=threadIdx.x;
  __shared__ float T[32][33];
  int lr=tid&31, lc=tid>>5;
  #pragma unroll
  for(int p=0;p<4;p++) T[lc+8*p][lr] = in[(long)(k0+lc+8*p)*N + n0+lr];
  __syncthreads();
  #pragma unroll
  for(int p=0;p<4;p++) out[(long)(n0+lc+8*p)*K + k0+lr] = f2b(T[lr][lc+8*p]);
}

// merged landmarks + v^T (both read only qkvb16). grid (132, 8, 2), 256 thr.
__global__ __launch_bounds__(256)
void k_lmvt(const u16* __restrict__ qkv16, u16* __restrict__ q_l, u16* __restrict__ k_l,
            u16* __restrict__ vT, float* __restrict__ colsum){
  int h = blockIdx.y, b = blockIdx.z, tid = threadIdx.x;
  __shared__ u16 T[64][72];
  if(blockIdx.x < 64){
    if(blockIdx.y==0 && blockIdx.z==0 && blockIdx.x<16) colsum[blockIdx.x*256 + tid] = 0.f;
    int j = blockIdx.x*4 + (tid>>6), d = tid&63;
    const u16* base = qkv16 + (long)b*NP*1536 + h*64 + d;
    float sq=0.f, sk=0.f;
    for(int l=0;l<17;l++){
      long row = (long)(j*17+l)*1536;
      sq += b2f(base[row]);
      sk += b2f(base[row+512]);
    }
    long o = (((long)b*HEADS + h)*LM + j)*DH + d;
    q_l[o] = f2b(sq * (SCALE/17.0f));
    k_l[o] = f2b(sk * (1.0f/17.0f));
  } else {
    int t0 = (blockIdx.x-64)*64;
    const u16* src = qkv16 + (long)b*NP*1536 + 1024 + h*64;
    for(int s=0;s<2;s++){
      int idx=tid+s*256; int row=idx>>3, c8=(idx&7)*8;
      *(us8*)&T[row][c8] = *(const us8*)&src[(long)(t0+row)*1536 + c8];
    }
    __syncthreads();
    u16* dst = vT + ((long)(b*8+h)*64)*NP;
    int d = tid>>2, j0=(tid&3)*16;
    us8 v0,v1;
    #pragma unroll
    for(int jj=0;jj<8;jj++){ v0[jj]=T[j0+jj][d]; v1[jj]=T[j0+8+jj][d]; }
    *(us8*)&dst[(long)d*NP + t0 + j0]     = v0;
    *(us8*)&dst[(long)d*NP + t0 + j0 + 8] = v1;
  }
}

__global__ void k_cvt16(const float* __restrict__ in, u16* __restrict__ out, long n){
  long i = (long)blockIdx.x*256 + threadIdx.x;
  if(i<n) out[i] = f2b(in[i]);
}

__global__ void k_cls(const float* __restrict__ cls, float* __restrict__ seq){
  int b = blockIdx.x;
  seq[(long)b*NTOK*EMB + threadIdx.x] = cls[threadIdx.x];
}

// LayerNorm of seq into xpb bf16 with 255 zero rows at front
__global__ void k_ln_pad(const float* __restrict__ seq, u16* __restrict__ xp,
                         const float* __restrict__ g, const float* __restrict__ bb){
  int b = blockIdx.y, i = blockIdx.x, tid = threadIdx.x;
  u16* out = xp + ((long)b*NP + i)*EMB;
  if(i < PADF){ out[tid]=0; out[tid+256]=0; return; }
  const float* x = seq + ((long)b*NTOK + (i-PADF))*EMB;
  float v0 = x[tid], v1 = x[tid+256];
  __shared__ float red[256];
  red[tid]=v0+v1; __syncthreads();
  for(int s=128;s>0;s>>=1){ if(tid<s) red[tid]+=red[tid+s]; __syncthreads(); }
  float mu = red[0]*(1.0f/512.0f); __syncthreads();
  float d0=v0-mu, d1=v1-mu;
  red[tid]=d0*d0+d1*d1; __syncthreads();
  for(int s=128;s>0;s>>=1){ if(tid<s) red[tid]+=red[tid+s]; __syncthreads(); }
  float rstd = rsqrtf(red[0]*(1.0f/512.0f) + 1e-5f);
  out[tid]     = f2b(d0*rstd*g[tid]     + bb[tid]);
  out[tid+256] = f2b(d1*rstd*g[tid+256] + bb[tid+256]);
}

// rm == 1 exactly (rows of a softmax sum to 1); cm = max over 16 heads x 256 cols.
__global__ void k_pair_init(const float* __restrict__ att2,
    const float* __restrict__ colsum,
    u16* __restrict__ Xh, u16* __restrict__ Xl,
    u16* __restrict__ Zh, u16* __restrict__ Zl,
    u16* __restrict__ Zth, u16* __restrict__ Ztl)
{
  long zo = (long)blockIdx.z*65536;
  int i0 = blockIdx.y*64, j0 = blockIdx.x*64;
  int tid = threadIdx.x;
  __shared__ float cred[256];
  {
    float cm = 0.f;
    #pragma unroll
    for(int i=0;i<16;i++) cm = fmaxf(cm, colsum[tid + i*256]);
    cred[tid] = cm; __syncthreads();
    for(int s=128;s>0;s>>=1){ if(tid<s) cred[tid]=fmaxf(cred[tid],cred[tid+s]); __syncthreads(); }
  }
  float inv = 1.0f/cred[0];
  __syncthreads();
  __shared__ float T[64][68];
  int li = tid>>2, jc = (tid&3)*16;
  #pragma unroll
  for(int u=0;u<4;u++){
    float4 v = *(const float4*)&att2[zo + (long)(i0+li)*256 + j0 + jc + u*4];
    T[li][jc+u*4]=v.x; T[li][jc+u*4+1]=v.y; T[li][jc+u*4+2]=v.z; T[li][jc+u*4+3]=v.w;
    long o = zo + (long)(i0+li)*256 + j0 + jc + u*4;
    float vv[4] = {v.x,v.y,v.z,v.w};
    us4 xh, xl, zth, ztl;
    #pragma unroll
    for(int c=0;c<4;c++){
      u16 h = f2b(vv[c]); xh[c]=h; xl[c]=f2b(vv[c]-b2f(h));
      float zt = vv[c]*inv;
      u16 h2 = f2b(zt); zth[c]=h2; ztl[c]=f2b(zt-b2f(h2));
    }
    *(us4*)&Xh[o]=xh; *(us4*)&Xl[o]=xl; *(us4*)&Zth[o]=zth; *(us4*)&Ztl[o]=ztl;
  }
  __syncthreads();
  int lj = tid>>2, ic = (tid&3)*16;
  #pragma unroll
  for(int r=0;r<16;r++){
    float x = T[ic+r][lj]*inv;
    u16 h = f2b(x);
    long o = zo + (long)(j0+lj)*256 + i0 + ic + r;
    Zh[o]=h; Zl[o]=f2b(x-b2f(h));
  }
}

// PPEG: 64-ch groups, 4 rows x 64 ch per block, x-split 2; grid (32, 8, 2)
__global__ __launch_bounds__(256)
void k_ppeg(const float* __restrict__ seq, float* __restrict__ out,
    const float* __restrict__ w7,const float* __restrict__ b7,
    const float* __restrict__ w5,const float* __restrict__ b5,
    const float* __restrict__ w3,const float* __restrict__ b3){
  int b = blockIdx.z, cg = blockIdx.y;
  int rp = blockIdx.x>>1, xs = blockIdx.x&1;
  int ch0 = cg*64;
  __shared__ float s7[64*49], s5[64*25], s3[64*9], sbias[64];
  int tid = threadIdx.x;
  for(int i=tid;i<64*49;i+=256) s7[i] = w7[ch0*49+i];
  for(int i=tid;i<64*25;i+=256) s5[i] = w5[ch0*25+i];
  for(int i=tid;i<64*9;i+=256)  s3[i] = w3[ch0*9+i];
  if(tid<64) sbias[tid] = b7[ch0+tid]+b5[ch0+tid]+b3[ch0+tid];
  if(cg==0 && blockIdx.x==0){
    out[(long)b*NTOK*EMB + tid]       = seq[(long)b*NTOK*EMB + tid];
    out[(long)b*NTOK*EMB + 256 + tid] = seq[(long)b*NTOK*EMB + 256 + tid];
  }
  __syncthreads();
  int c = tid & 63;
  int y = rp*4 + (tid>>6);
  const float* sbase = seq + (long)b*NTOK*EMB + EMB + (ch0 + c);
  float* obase = out + (long)b*NTOK*EMB + EMB + (ch0 + c);
  const float* W7 = &s7[c*49];
  const float* W5 = &s5[c*25];
  const float* W3 = &s3[c*9];
  float bsum = sbias[c];
  for(int xc=0;xc<4;xc++){
    int xb = xs*32 + xc*8;
    float acc[8];
    #pragma unroll
    for(int j=0;j<8;j++) acc[j] = sbase[(long)(y*64+xb+j)*EMB] + bsum;
    #pragma unroll
    for(int dy=-3;dy<=3;dy++){
      int yy = y+dy;
      if(yy<0||yy>=64) continue;
      float v[14];
      #pragma unroll
      for(int u=0;u<14;u++){
        int xx = xb + u - 3;
        v[u] = (xx>=0 && xx<64) ? sbase[(long)(yy*64+xx)*EMB] : 0.f;
      }
      #pragma unroll
      for(int dx=-3;dx<=3;dx++){
        float wsum = W7[(dy+3)*7+(dx+3)];
        if(dy>=-2&&dy<=2&&dx>=-2&&dx<=2) wsum += W5[(dy+2)*5+(dx+2)];
        if(dy>=-1&&dy<=1&&dx>=-1&&dx<=1) wsum += W3[(dy+1)*3+(dx+1)];
        #pragma unroll
        for(int j=0;j<8;j++) acc[j] += v[j+dx+3]*wsum;
      }
    }
    #pragma unroll
    for(int j=0;j<8;j++) obase[(long)(y*64+xb+j)*EMB] = acc[j];
  }
}

__global__ void k_final_ln(const float* __restrict__ seq, const float* __restrict__ g,
                           const float* __restrict__ bb, float* __restrict__ out){
  int b = blockIdx.x, tid = threadIdx.x;
  const float* x = seq + (long)b*NTOK*EMB;
  float v0 = x[tid], v1 = x[tid+256];
  __shared__ float red[256];
  red[tid]=v0+v1; __syncthreads();
  for(int s=128;s>0;s>>=1){ if(tid<s) red[tid]+=red[tid+s]; __syncthreads(); }
  float mu = red[0]*(1.0f/512.0f); __syncthreads();
  float d0=v0-mu, d1=v1-mu;
  red[tid]=d0*d0+d1*d1; __syncthreads();
  for(int s=128;s>0;s>>=1){ if(tid<s) red[tid]+=red[tid+s]; __syncthreads(); }
  float rstd = rsqrtf(red[0]*(1.0f/512.0f) + 1e-5f);
  out[b*512+tid]     = d0*rstd*g[tid]     + bb[tid];
  out[b*512+tid+256] = d1*rstd*g[tid+256] + bb[tid+256];
}

// ---------------- host ----------------
extern "C" void kernel_launch(void* const* d_in, const int* in_sizes, int n_in,
                              void* d_out, int out_size, void* d_ws, size_t ws_size,
                              hipStream_t stream) {
  const float* in[24];
  for(int i=0;i<24;i++) in[i] = (const float*)d_in[i];

  float* W = (float*)d_ws;
  size_t off = 0;
  float* seqA = W+off; off += 4195328;        // 2*4097*512
  float* seqB = W+off; off += 4195328;
  float* att2 = W+off; off += 1048576;        // 16*65536
  float* partO= W+off; off += 17825792;       // 16*17*256*64
  float* pm   = W+off; off += 69632;
  float* pl   = W+off; off += 69632;
  u16* xpb    = (u16*)(W+off); off += 2228224;  // 2*4352*512 u16
  u16* qkvb16 = (u16*)(W+off); off += 6684672;  // 2*4352*1536 u16
  u16* vT16   = (u16*)(W+off); off += 2228224;
  u16* q_l16  = (u16*)(W+off); off += 131072;   // 16*256*64 u16
  u16* k_l16  = (u16*)(W+off); off += 131072;
  u16* avbT16 = (u16*)(W+off); off += 131072;
  u16* zavT16 = (u16*)(W+off); off += 131072;
  u16* Qc16   = (u16*)(W+off); off += 2228224;
  u16* qkvwT1 = (u16*)(W+off); off += 393216;   // 1536*512 u16
  u16* qkvwT2 = (u16*)(W+off); off += 393216;
  u16* outwT1 = (u16*)(W+off); off += 131072;   // 512*512 u16
  u16* outwT2 = (u16*)(W+off); off += 131072;
  u16* pairs  = (u16*)(W+off); off += 9437184;  // 18*16*65536 u16
  float* colsum = W+off; off += 4096;           // 16*256
  if (ws_size < off*sizeof(float)) return;

  // h16/wfc1T alias the pairs region (pairs first written at pair_init, after fc1)
  u16* h16   = pairs;
  u16* wfc1T = pairs + 8388608;

  const long PB = 1048576;  // 16*65536
  u16 *Xh=pairs,        *Xl=pairs+PB;
  u16 *Z0h=pairs+2*PB,  *Z0l=pairs+3*PB;
  u16 *Z0th=pairs+4*PB, *Z0tl=pairs+5*PB;
  u16 *Z1h=pairs+6*PB,  *Z1l=pairs+7*PB;
  u16 *P0h=pairs+8*PB,  *P0l=pairs+9*PB;
  u16 *P1h=pairs+10*PB, *P1l=pairs+11*PB;
  u16 *Tth=pairs+12*PB, *Ttl=pairs+13*PB;
  u16 *Uth=pairs+14*PB, *Utl=pairs+15*PB;
  u16 *Vth=pairs+16*PB, *Vtl=pairs+17*PB;

  // weight conversions/transposes
  k_cvt16<<<32768,256,0,stream>>>(in[0], h16, 8388608L);
  k_wT<<<dim3(16,32),256,0,stream>>>(in[1],  wfc1T, 1024, 512);
  k_wT<<<dim3(48,16),256,0,stream>>>(in[6],  qkvwT1, 512, 1536);
  k_wT<<<dim3(48,16),256,0,stream>>>(in[18], qkvwT2, 512, 1536);
  k_wT<<<dim3(16,16),256,0,stream>>>(in[7],  outwT1, 512, 512);
  k_wT<<<dim3(16,16),256,0,stream>>>(in[19], outwT2, 512, 512);

  // fc1 + cls (64x64 tiles -> 1024 blocks = 4/CU)
  k_g64<6><<<dim3(8,64,2),256,0,stream>>>(h16, wfc1T, seqA+EMB, nullptr,
      1024, 1024,1024,512, 4194304L,0, 0,0, (long)NTOK*EMB,0, 1, 1.0f, in[2], 0, 0, 8, 1);
  k_cls<<<2,512,0,stream>>>(in[3], seqA);

  auto attention = [&](float* seq, const float* lng,const float* lnb,
                       const u16* qkvwT, const u16* outwT, const float* outb, const float* resk){
    k_ln_pad<<<dim3(NP,2),256,0,stream>>>(seq, xpb, lng, lnb);
    k_g128<2><<<dim3(12,34,2),256,0,stream>>>(xpb, qkvwT, nullptr, qkvb16,
        512, 512,512,1536, (long)NP*512,0, 0,0, (long)NP*1536,0, 1, 1.0f, nullptr, 0, 0, 12, 1);
    // merged landmarks + vT (+ colsum zero)
    k_lmvt<<<dim3(132,HEADS,2),256,0,stream>>>(qkvb16, q_l16, k_l16, vT16, colsum);
    // fused attn2: scores + row-softmax -> att2 fp32, column sums -> colsum
    k_att2f<<<dim3(4,16),256,0,stream>>>(q_l16, k_l16, att2, colsum);
    // pinv on bf16 pairs, y-recurrence form:
    //   y0 = X@Z0;  per iter: U=15I-y@T, V=13I-y@U, z'=0.25 Z@V, y'=0.25 y@V (fused)
    k_pair_init<<<dim3(4,4,16),256,0,stream>>>(att2, colsum, Xh,Xl, Z0h,Z0l, Z0th,Z0tl);
    dim3 pgrid(4,8,16);
    k_pg3<<<pgrid,256,0,stream>>>(Xh,Xl, Z0th,Z0tl, P0h,P0l,1.0f,0.f, Tth,Ttl,-1.0f,7.f);
    for(int it=0; it<6; it++){
      u16 *Zh_=(it&1)?Z1h:Z0h, *Zl_=(it&1)?Z1l:Z0l;
      u16 *Nh_=(it&1)?Z0h:Z1h, *Nl_=(it&1)?Z0l:Z1l;
      u16 *Pch=(it&1)?P1h:P0h, *Pcl=(it&1)?P1l:P0l;
      u16 *Pnh=(it&1)?P0h:P1h, *Pnl=(it&1)?P0l:P1l;
      k_pg3<<<pgrid,256,0,stream>>>(Pch,Pcl, Tth,Ttl, nullptr,nullptr,0.f,0.f, Uth,Utl,-1.0f,15.f);
      k_pg3<<<pgrid,256,0,stream>>>(Pch,Pcl, Uth,Utl, nullptr,nullptr,0.f,0.f, Vth,Vtl,-1.0f,13.f);
      if(it<5) k_pg3b<<<dim3(4,16,16),256,0,stream>>>(Zh_,Zl_, Pch,Pcl, Vth,Vtl,
                                                      Nh_,Nl_, Pnh,Pnl, Tth,Ttl);
      else     k_pg3<<<pgrid,256,0,stream>>>(Zh_,Zl_, Vth,Vtl, Nh_,Nl_,0.25f,0.f,
                                             nullptr,nullptr,0.f,0.f);
    }
    // fused flash attn3@v: 17 token-chunks x 4 q-tiles x 16 heads, swizzled LDS
    k_att3<<<dim3(17,4,16),256,0,stream>>>(qkvb16, q_l16, vT16, partO, pm, pl);
    k_mrg3<<<dim3(16,16),128,0,stream>>>(partO, pm, pl, avbT16);
    // zavT = avbT @ Z^T  -> bf16
    k_g64<2><<<dim3(4,1,16),256,0,stream>>>(avbT16, Z0h, nullptr, zavT16,
        256, 256,256,256, 0,16384L, 0,65536L, 0,16384L, 16, 1.0f, nullptr, 0, 0, 4, 1);
    // fused attn1 + res-conv: scores + softmax + @zav + dwconv -> Qc16 (bf16)
    k_att1<<<dim3(68,16),256,0,stream>>>(qkvb16, k_l16, zavT16, resk, Qc16);
    // out proj + residual add into seq: 64x64 tiles, no split-K, no atomics.
    k_g64<5><<<dim3(8,65,2),256,0,stream>>>(Qc16, outwT, seq, nullptr,
        512, 512,512,512, (long)NP*512,0, 0,0, (long)NTOK*EMB,0, 1, 1.0f, outb, PADF, 192, 8, 1);
  };

  attention(seqA, in[4], in[5], qkvwT1, outwT1, in[8], in[9]);
  k_ppeg<<<dim3(32,8,2),256,0,stream>>>(seqA, seqB, in[10],in[11],in[12],in[13],in[14],in[15]);
  attention(seqB, in[16], in[17], qkvwT2, outwT2, in[20], in[21]);
  k_final_ln<<<2,256,0,stream>>>(seqB, in[22], in[23], (float*)d_out);
}

// Round 11
// 831.367 us; speedup vs baseline: 1.0204x; 1.0204x over previous
//
#include <hip/hip_runtime.h>
#include <hip/hip_bf16.h>

#define HEADS 8
#define DH 64
#define EMB 512
#define NP 4352
#define NTOK 4097
#define PADF 255
#define LM 256
#define SCALE 0.125f

typedef __attribute__((ext_vector_type(8))) short bf8;
typedef __attribute__((ext_vector_type(4))) float f4;
typedef __attribute__((ext_vector_type(8))) unsigned short us8;
typedef __attribute__((ext_vector_type(4))) unsigned short us4;
typedef unsigned short u16;

__device__ __forceinline__ u16 f2b(float f){
  union { float f; unsigned u; } x; x.f = f;
  unsigned r = x.u + 0x7fffu + ((x.u>>16)&1u);
  return (u16)(r>>16);
}
__device__ __forceinline__ float b2f(u16 h){
  union { unsigned u; float f; } x; x.u = ((unsigned)h)<<16;
  return x.f;
}

__device__ __forceinline__ void gload_lds(const u16* g, u16* l){
  __builtin_amdgcn_global_load_lds((const __attribute__((address_space(1))) void*)g,
                                   (__attribute__((address_space(3))) void*)l, 16, 0, 0);
}

// counted-vmcnt pipeline helpers (depth-3): wait for the OLDEST tile's loads only.
#define WAITCNT(N) asm volatile("s_waitcnt vmcnt(" #N ")" ::: "memory")
#define SCHED_FENCE() __builtin_amdgcn_sched_barrier(0)
#define BARRIER() __builtin_amdgcn_s_barrier()

// ======== 128x128 NT bf16 GEMM, BK=32, depth-3 counted-vmcnt pipeline ========
// MODE 0: fp32 store; MODE 2: bf16 store; MODE 3: fp32 C[gm-rowoff] += v;
// MODE 4: fp32 atomicAdd to C[gm-rowoff] (split-K safe; bias only on kc==0)
template<int MODE>
__global__ __launch_bounds__(256)
void k_g128(const u16* __restrict__ A, const u16* __restrict__ B,
            float* __restrict__ C, u16* __restrict__ C16,
            int K, int lda, int ldb, int ldc,
            long sAb, long sAh, long sBb, long sBh, long sCb, long sCh, int nh,
            float alpha, const float* __restrict__ bias, int relu, int rowoff,
            int nx, int ksplit)
{
  int z = blockIdx.z;
  const u16* Ab = A + (long)(z/nh)*sAb + (long)(z%nh)*sAh;
  const u16* Bb = B + (long)(z/nh)*sBb + (long)(z%nh)*sBh;
  long cb = (long)(z/nh)*sCb + (long)(z%nh)*sCh;
  int bx = blockIdx.x % nx, kc = blockIdx.x / nx;
  int m0 = blockIdx.y*128, n0 = bx*128;
  int klen = K/ksplit, kbeg = kc*klen, nch = klen/32;
  __shared__ u16 As[3][4096];
  __shared__ u16 Bs[3][4096];
  int tid=threadIdx.x, w=tid>>6, lane=tid&63, q=lane>>4, lr=lane&15;
  int wrow=(w>>1)*64, wcol=(w&1)*64;
  int srow = tid>>2, scol = (tid&3)*8;
  const u16* ga  = Ab + (long)(m0+srow)*lda + kbeg + scol;
  const u16* ga2 = Ab + (long)(m0+64+srow)*lda + kbeg + scol;
  const u16* gb  = Bb + (long)(n0+srow)*ldb + kbeg + scol;
  const u16* gb2 = Bb + (long)(n0+64+srow)*ldb + kbeg + scol;
  int lo = srow*32 + scol;
  f4 acc[4][4] = {};
  auto stage = [&](int r, int c){
    gload_lds(ga  + c*32, &As[r][lo]);
    gload_lds(ga2 + c*32, &As[r][2048+lo]);
    gload_lds(gb  + c*32, &Bs[r][lo]);
    gload_lds(gb2 + c*32, &Bs[r][2048+lo]);
  };
  auto compute = [&](int r){
    bf8 af[4], bfr[4];
    #pragma unroll
    for(int rr=0;rr<4;rr++) af[rr]  = *(const bf8*)&As[r][(wrow + rr*16 + lr)*32 + q*8];
    #pragma unroll
    for(int t=0;t<4;t++) bfr[t] = *(const bf8*)&Bs[r][(wcol + t*16 + lr)*32 + q*8];
    #pragma unroll
    for(int rr=0;rr<4;rr++)
      #pragma unroll
      for(int t=0;t<4;t++)
        acc[rr][t] = __builtin_amdgcn_mfma_f32_16x16x32_bf16(af[rr], bfr[t], acc[rr][t], 0,0,0);
  };
  stage(0,0);
  if(nch>1) stage(1,1);
  if(nch>2) stage(2,2);
  int bufc = 0;
  for(int c=0;c<nch;c++){
    int rem = nch-1-c;
    if(rem>=2) WAITCNT(8); else if(rem==1) WAITCNT(4); else WAITCNT(0);
    SCHED_FENCE();
    BARRIER();
    compute(bufc);
    SCHED_FENCE();
    BARRIER();
    SCHED_FENCE();
    if(c+3<nch) stage(bufc, c+3);
    bufc = (bufc+1==3)?0:bufc+1;
  }
  #pragma unroll
  for(int r=0;r<4;r++){
    #pragma unroll
    for(int t=0;t<4;t++){
      #pragma unroll
      for(int e=0;e<4;e++){
        int gm = m0 + wrow + r*16 + q*4 + e;
        int gn = n0 + wcol + t*16 + lr;
        float v = acc[r][t][e]*alpha;
        if(MODE==4){
          if(bias && kc==0) v += bias[gn];
          if(gm>=rowoff) atomicAdd(&C[cb + (long)(gm-rowoff)*ldc + gn], v);
        } else {
          if(bias) v += bias[gn];
          if(relu) v = fmaxf(v,0.f);
          if(MODE==0) C[cb + (long)gm*ldc + gn] = v;
          else if(MODE==2) C16[cb + (long)gm*ldc + gn] = f2b(v);
          else { if(gm>=rowoff) C[cb + (long)(gm-rowoff)*ldc + gn] += v; }
        }
      }
    }
  }
}

// ======== 64x64 NT bf16 GEMM, depth-3 counted-vmcnt pipeline ========
// MODE 0: fp32 store; MODE 2: bf16 store; MODE 3: fp32 atomicAdd
// MODE 5: fp32 C[gm-rowoff] += v + bias (non-atomic; requires ksplit==1)
// MODE 6: fp32 C = relu(v + bias)
template<int MODE>
__global__ __launch_bounds__(256)
void k_g64(const u16* __restrict__ A, const u16* __restrict__ B,
           float* __restrict__ C, u16* __restrict__ C16,
           int K, int lda, int ldb, int ldc,
           long sAb, long sAh, long sBb, long sBh, long sCb, long sCh, int nh,
           float alpha, const float* __restrict__ bias, int rowoff, int moff,
           int nx, int ksplit)
{
  int z = blockIdx.z;
  const u16* Ab = A + (long)(z/nh)*sAb + (long)(z%nh)*sAh;
  const u16* Bb = B + (long)(z/nh)*sBb + (long)(z%nh)*sBh;
  long cb = (long)(z/nh)*sCb + (long)(z%nh)*sCh;
  int bx = blockIdx.x % nx, kc = blockIdx.x / nx;
  int m0 = blockIdx.y*64 + moff, n0 = bx*64;
  int klen = K/ksplit, kbeg = kc*klen, nch = klen/32;
  __shared__ u16 As[3][2048];
  __shared__ u16 Bs[3][2048];
  int tid=threadIdx.x, w=tid>>6, lane=tid&63, q=lane>>4, lr=lane&15;
  int srow = tid>>2, scol = (tid&3)*8;
  const u16* ga = Ab + (long)(m0+srow)*lda + kbeg + scol;
  const u16* gb = Bb + (long)(n0+srow)*ldb + kbeg + scol;
  int lo = srow*32 + scol;
  f4 acc[4] = {};
  auto stage = [&](int r, int c){
    gload_lds(ga + c*32, &As[r][lo]);
    gload_lds(gb + c*32, &Bs[r][lo]);
  };
  auto compute = [&](int r){
    bf8 af = *(const bf8*)&As[r][(w*16 + lr)*32 + q*8];
    #pragma unroll
    for(int t=0;t<4;t++){
      bf8 bfr = *(const bf8*)&Bs[r][(t*16 + lr)*32 + q*8];
      acc[t] = __builtin_amdgcn_mfma_f32_16x16x32_bf16(af, bfr, acc[t], 0,0,0);
    }
  };
  stage(0,0);
  if(nch>1) stage(1,1);
  if(nch>2) stage(2,2);
  int bufc = 0;
  for(int c=0;c<nch;c++){
    int rem = nch-1-c;
    if(rem>=2) WAITCNT(4); else if(rem==1) WAITCNT(2); else WAITCNT(0);
    SCHED_FENCE();
    BARRIER();
    compute(bufc);
    SCHED_FENCE();
    BARRIER();
    SCHED_FENCE();
    if(c+3<nch) stage(bufc, c+3);
    bufc = (bufc+1==3)?0:bufc+1;
  }
  #pragma unroll
  for(int t=0;t<4;t++){
    #pragma unroll
    for(int e=0;e<4;e++){
      int gm = m0 + w*16 + q*4 + e;
      int gn = n0 + t*16 + lr;
      float v = acc[t][e]*alpha;
      if(MODE==0) C[cb + (long)gm*ldc + gn] = v;
      else if(MODE==2) C16[cb + (long)gm*ldc + gn] = f2b(v);
      else if(MODE==3) atomicAdd(&C[cb + (long)gm*ldc + gn], v);
      else if(MODE==5){
        v += bias[gn];
        if(gm>=rowoff) C[cb + (long)(gm-rowoff)*ldc + gn] += v;
      }
      else if(MODE==6){
        v = fmaxf(v + bias[gn], 0.f);
        C[cb + (long)gm*ldc + gn] = v;
      }
    }
  }
}

// ======== pinv GEMM on bf16 hi/lo pairs — 32x64 strips, depth-3 pipeline ========
__global__ __launch_bounds__(256)
void k_pg3(const u16* __restrict__ Ah, const u16* __restrict__ Al,
           const u16* __restrict__ Bh, const u16* __restrict__ Bl,
           u16* __restrict__ Oh, u16* __restrict__ Ol, float na, float nd,
           u16* __restrict__ TOh, u16* __restrict__ TOl, float ta, float td)
{
  long zo = (long)blockIdx.z*65536;
  int m0 = blockIdx.y*32, n0 = blockIdx.x*64;
  __shared__ u16 S[3][6144];
  int tid=threadIdx.x, w=tid>>6, lane=tid&63, q=lane>>4, lr=lane&15;
  int t2 = tid & 127;
  const u16* srcA = (tid<128 ? Ah : Al) + zo + (long)(m0 + (t2>>2))*256 + (t2&3)*8;
  const u16* srcBh = Bh + zo + (long)(n0 + (tid>>2))*256 + (tid&3)*8;
  const u16* srcBl = Bl + zo + (long)(n0 + (tid>>2))*256 + (tid&3)*8;
  f4 acc[2] = {};
  auto stage = [&](int r, int c){
    gload_lds(srcA  + c*32, &S[r][tid*8]);
    gload_lds(srcBh + c*32, &S[r][2048 + tid*8]);
    gload_lds(srcBl + c*32, &S[r][4096 + tid*8]);
  };
  int mrow = (w>>1)*16 + lr;
  auto compute = [&](int r){
    bf8 ah = *(const bf8*)&S[r][mrow*32 + q*8];
    bf8 al = *(const bf8*)&S[r][1024 + mrow*32 + q*8];
    #pragma unroll
    for(int t=0;t<2;t++){
      int nrow = (w&1)*32 + t*16 + lr;
      bf8 bh = *(const bf8*)&S[r][2048 + nrow*32 + q*8];
      bf8 bl = *(const bf8*)&S[r][4096 + nrow*32 + q*8];
      acc[t] = __builtin_amdgcn_mfma_f32_16x16x32_bf16(ah, bh, acc[t], 0,0,0);
      acc[t] = __builtin_amdgcn_mfma_f32_16x16x32_bf16(ah, bl, acc[t], 0,0,0);
      acc[t] = __builtin_amdgcn_mfma_f32_16x16x32_bf16(al, bh, acc[t], 0,0,0);
    }
  };
  stage(0,0);
  stage(1,1);
  stage(2,2);
  int bufc = 0;
  for(int c=0;c<8;c++){
    int rem = 7-c;
    if(rem>=2) WAITCNT(6); else if(rem==1) WAITCNT(3); else WAITCNT(0);
    SCHED_FENCE();
    BARRIER();
    compute(bufc);
    SCHED_FENCE();
    BARRIER();
    SCHED_FENCE();
    if(c+3<8) stage(bufc, c+3);
    bufc = (bufc+1==3)?0:bufc+1;
  }
  #pragma unroll
  for(int t=0;t<2;t++){
    int gn = n0 + (w&1)*32 + t*16 + lr;
    if(Oh){
      #pragma unroll
      for(int r=0;r<4;r++){
        int gm = m0 + (w>>1)*16 + q*4 + r;
        float v = na*acc[t][r] + ((gm==gn)?nd:0.f);
        u16 h = f2b(v);
        long o = zo + (long)gm*256 + gn;
        Oh[o] = h; Ol[o] = f2b(v - b2f(h));
      }
    }
    if(TOh){
      us4 th, tl;
      #pragma unroll
      for(int r=0;r<4;r++){
        int gm = m0 + (w>>1)*16 + q*4 + r;
        float v = ta*acc[t][r] + ((gm==gn)?td:0.f);
        u16 h = f2b(v);
        th[r] = h; tl[r] = f2b(v - b2f(h));
      }
      long o = zo + (long)gn*256 + (m0 + (w>>1)*16 + q*4);
      *(us4*)&TOh[o] = th; *(us4*)&TOl[o] = tl;
    }
  }
}

// ======== dual-A pinv GEMM: half grid computes z_new=0.25*Z@V, half computes
// y_new=0.25*P@V (+ T_new = 7I - y_new transposed). grid (4,16,16). ========
__global__ __launch_bounds__(256)
void k_pg3b(const u16* __restrict__ Zh, const u16* __restrict__ Zl,
            const u16* __restrict__ Ph, const u16* __restrict__ Pl,
            const u16* __restrict__ Bh, const u16* __restrict__ Bl,
            u16* __restrict__ Ozh, u16* __restrict__ Ozl,
            u16* __restrict__ Oyh, u16* __restrict__ Oyl,
            u16* __restrict__ Tyh, u16* __restrict__ Tyl)
{
  long zo = (long)blockIdx.z*65536;
  int ysel = blockIdx.y>>3;
  int m0 = (blockIdx.y&7)*32, n0 = blockIdx.x*64;
  const u16* Ah = ysel ? Ph : Zh;
  const u16* Al = ysel ? Pl : Zl;
  __shared__ u16 S[3][6144];
  int tid=threadIdx.x, w=tid>>6, lane=tid&63, q=lane>>4, lr=lane&15;
  int t2 = tid & 127;
  const u16* srcA = (tid<128 ? Ah : Al) + zo + (long)(m0 + (t2>>2))*256 + (t2&3)*8;
  const u16* srcBh = Bh + zo + (long)(n0 + (tid>>2))*256 + (tid&3)*8;
  const u16* srcBl = Bl + zo + (long)(n0 + (tid>>2))*256 + (tid&3)*8;
  f4 acc[2] = {};
  auto stage = [&](int r, int c){
    gload_lds(srcA  + c*32, &S[r][tid*8]);
    gload_lds(srcBh + c*32, &S[r][2048 + tid*8]);
    gload_lds(srcBl + c*32, &S[r][4096 + tid*8]);
  };
  int mrow = (w>>1)*16 + lr;
  auto compute = [&](int r){
    bf8 ah = *(const bf8*)&S[r][mrow*32 + q*8];
    bf8 al = *(const bf8*)&S[r][1024 + mrow*32 + q*8];
    #pragma unroll
    for(int t=0;t<2;t++){
      int nrow = (w&1)*32 + t*16 + lr;
      bf8 bh = *(const bf8*)&S[r][2048 + nrow*32 + q*8];
      bf8 bl = *(const bf8*)&S[r][4096 + nrow*32 + q*8];
      acc[t] = __builtin_amdgcn_mfma_f32_16x16x32_bf16(ah, bh, acc[t], 0,0,0);
      acc[t] = __builtin_amdgcn_mfma_f32_16x16x32_bf16(ah, bl, acc[t], 0,0,0);
      acc[t] = __builtin_amdgcn_mfma_f32_16x16x32_bf16(al, bh, acc[t], 0,0,0);
    }
  };
  stage(0,0);
  stage(1,1);
  stage(2,2);
  int bufc = 0;
  for(int c=0;c<8;c++){
    int rem = 7-c;
    if(rem>=2) WAITCNT(6); else if(rem==1) WAITCNT(3); else WAITCNT(0);
    SCHED_FENCE();
    BARRIER();
    compute(bufc);
    SCHED_FENCE();
    BARRIER();
    SCHED_FENCE();
    if(c+3<8) stage(bufc, c+3);
    bufc = (bufc+1==3)?0:bufc+1;
  }
  #pragma unroll
  for(int t=0;t<2;t++){
    int gn = n0 + (w&1)*32 + t*16 + lr;
    if(!ysel){
      #pragma unroll
      for(int r=0;r<4;r++){
        int gm = m0 + (w>>1)*16 + q*4 + r;
        float v = 0.25f*acc[t][r];
        u16 h = f2b(v);
        long o = zo + (long)gm*256 + gn;
        Ozh[o] = h; Ozl[o] = f2b(v - b2f(h));
      }
    } else {
      us4 th, tl;
      #pragma unroll
      for(int r=0;r<4;r++){
        int gm = m0 + (w>>1)*16 + q*4 + r;
        float v = 0.25f*acc[t][r];
        u16 h = f2b(v);
        long o = zo + (long)gm*256 + gn;
        Oyh[o] = h; Oyl[o] = f2b(v - b2f(h));
        float tv = -v + ((gm==gn)?7.f:0.f);
        u16 h2 = f2b(tv);
        th[r] = h2; tl[r] = f2b(tv - b2f(h2));
      }
      long o = zo + (long)gn*256 + (m0 + (w>>1)*16 + q*4);
      *(us4*)&Tyh[o] = th; *(us4*)&Tyl[o] = tl;
    }
  }
}

// ======== fused attn2: S=q_l@k_l^T; P=softmax(S) -> att2 fp32; colsum atomicAdd ===
// grid (4 m-tiles, 16 z), 256 thr. q_l pre-scaled by SCALE (landmarks). Swizzled LDS.
__global__ __launch_bounds__(256)
void k_att2f(const u16* __restrict__ ql, const u16* __restrict__ kl,
             float* __restrict__ att2, float* __restrict__ colsum)
{
  int z = blockIdx.y;
  int m0 = blockIdx.x*64;
  __shared__ u16 SQ[64*64];
  __shared__ u16 SKL[256*64];
  int tid=threadIdx.x, w=tid>>6, lane=tid&63, q=lane>>4, lr=lane&15;
  {
    const u16* qb = ql + (long)z*16384 + m0*64;
    #pragma unroll
    for(int p=0;p<2;p++){
      int idx = tid + p*256; int row = idx>>3; int js = ((idx&7)^(row&7))<<3;
      gload_lds(qb + row*64 + js, &SQ[idx*8]);
    }
    const u16* kb = kl + (long)z*16384;
    #pragma unroll
    for(int p=0;p<8;p++){
      int idx = tid + p*256; int row = idx>>3; int js = ((idx&7)^(row&7))<<3;
      gload_lds(kb + row*64 + js, &SKL[idx*8]);
    }
  }
  __syncthreads();
  f4 acc[16] = {};
  {
    int ar = w*16+lr;
    bf8 af0 = *(const bf8*)&SQ[ar*64 + ((q^(ar&7))<<3)];
    bf8 af1 = *(const bf8*)&SQ[ar*64 + (((q|4)^(ar&7))<<3)];
    #pragma unroll
    for(int t=0;t<16;t++){
      int br = t*16+lr;
      bf8 b0 = *(const bf8*)&SKL[br*64 + ((q^(br&7))<<3)];
      bf8 b1 = *(const bf8*)&SKL[br*64 + (((q|4)^(br&7))<<3)];
      acc[t] = __builtin_amdgcn_mfma_f32_16x16x32_bf16(af0, b0, acc[t], 0,0,0);
      acc[t] = __builtin_amdgcn_mfma_f32_16x16x32_bf16(af1, b1, acc[t], 0,0,0);
    }
  }
  float mx[4] = {-1e30f,-1e30f,-1e30f,-1e30f};
  #pragma unroll
  for(int t=0;t<16;t++)
    #pragma unroll
    for(int e=0;e<4;e++) mx[e] = fmaxf(mx[e], acc[t][e]);
  #pragma unroll
  for(int s=1;s<16;s<<=1)
    #pragma unroll
    for(int e=0;e<4;e++) mx[e] = fmaxf(mx[e], __shfl_xor(mx[e], s));
  float sm[4] = {0.f,0.f,0.f,0.f};
  #pragma unroll
  for(int t=0;t<16;t++)
    #pragma unroll
    for(int e=0;e<4;e++){ float p = expf(acc[t][e] - mx[e]); acc[t][e]=p; sm[e]+=p; }
  #pragma unroll
  for(int s=1;s<16;s<<=1)
    #pragma unroll
    for(int e=0;e<4;e++) sm[e] += __shfl_xor(sm[e], s);
  float inv[4];
  #pragma unroll
  for(int e=0;e<4;e++) inv[e] = 1.f/sm[e];
  float* ab = att2 + (long)z*65536;
  #pragma unroll
  for(int t=0;t<16;t++){
    float cs = 0.f;
    #pragma unroll
    for(int e=0;e<4;e++){
      float p = acc[t][e]*inv[e];
      ab[(long)(m0 + w*16 + q*4 + e)*256 + t*16 + lr] = p;
      cs += p;
    }
    cs += __shfl_xor(cs, 16);
    cs += __shfl_xor(cs, 32);
    if(q==0) atomicAdd(&colsum[z*256 + t*16 + lr], cs);
  }
}

// ======== fused attn3@v flash: partial softmax(q_l@k^T)@v over 256-token chunks ===
// grid (kc=17, jt=4, z=16), 256 thr (4 waves x 16 q-rows). 4-iteration online loop.
// All LDS tiles XOR-swizzled (linear dest + pre-swizzled global source).
__global__ __launch_bounds__(256)
void k_att3(const u16* __restrict__ qkv16, const u16* __restrict__ ql,
            const u16* __restrict__ vT, float* __restrict__ partO,
            float* __restrict__ pm, float* __restrict__ pl)
{
  int kc = blockIdx.x, jt = blockIdx.y, z = blockIdx.z;
  int b = z>>3, h = z&7;
  __shared__ u16 SQ[64*64];
  __shared__ u16 SK[2][64*64];
  __shared__ u16 SV[2][64*64];
  __shared__ u16 SP[64*64];
  int tid=threadIdx.x, w=tid>>6, lane=tid&63, q=lane>>4, lr=lane&15;
  const u16* kb = qkv16 + (long)b*NP*1536 + 512 + h*64;
  const u16* vb = vT + (long)z*64*NP;
  int t00 = kc*256;
  {
    const u16* qb = ql + (long)z*16384 + jt*64*64;
    #pragma unroll
    for(int p=0;p<2;p++){
      int idx = tid + p*256; int row = idx>>3; int js = ((idx&7)^(row&7))<<3;
      gload_lds(qb + row*64 + js, &SQ[idx*8]);
    }
  }
  auto stageKV = [&](int r, int i){
    int t0 = t00 + i*64;
    #pragma unroll
    for(int p=0;p<2;p++){
      int idx = tid + p*256; int row = idx>>3; int js = ((idx&7)^(row&7))<<3;
      gload_lds(kb + (long)(t0+row)*1536 + js, &SK[r][idx*8]);
      gload_lds(vb + (long)row*NP + t0 + js, &SV[r][idx*8]);
    }
  };
  stageKV(0,0);
  __syncthreads();
  int ar = w*16+lr;
  bf8 af0 = *(const bf8*)&SQ[ar*64 + ((q^(ar&7))<<3)];
  bf8 af1 = *(const bf8*)&SQ[ar*64 + (((q|4)^(ar&7))<<3)];
  f4 o[4] = {};
  float m[4] = {-3e38f,-3e38f,-3e38f,-3e38f};
  float l[4] = {0.f,0.f,0.f,0.f};
  for(int i=0;i<4;i++){
    int cur = i&1;
    if(i<3) stageKV(cur^1, i+1);
    f4 s[4] = {};
    #pragma unroll
    for(int t=0;t<4;t++){
      int br = t*16+lr;
      bf8 b0 = *(const bf8*)&SK[cur][br*64 + ((q^(br&7))<<3)];
      bf8 b1 = *(const bf8*)&SK[cur][br*64 + (((q|4)^(br&7))<<3)];
      s[t] = __builtin_amdgcn_mfma_f32_16x16x32_bf16(af0, b0, s[t], 0,0,0);
      s[t] = __builtin_amdgcn_mfma_f32_16x16x32_bf16(af1, b1, s[t], 0,0,0);
    }
    float tm[4];
    #pragma unroll
    for(int e=0;e<4;e++) tm[e] = fmaxf(fmaxf(s[0][e],s[1][e]), fmaxf(s[2][e],s[3][e]));
    #pragma unroll
    for(int sh=1; sh<16; sh<<=1)
      #pragma unroll
      for(int e=0;e<4;e++) tm[e] = fmaxf(tm[e], __shfl_xor(tm[e], sh));
    float rs[4];
    #pragma unroll
    for(int e=0;e<4;e++){
      float mn = fmaxf(m[e], tm[e]);
      float sc = expf(m[e]-mn);
      m[e] = mn;
      l[e] *= sc;
      rs[e] = 0.f;
      o[0][e]*=sc; o[1][e]*=sc; o[2][e]*=sc; o[3][e]*=sc;
    }
    #pragma unroll
    for(int t=0;t<4;t++)
      #pragma unroll
      for(int e=0;e<4;e++){
        float p = expf(s[t][e]-m[e]);
        rs[e] += p;
        int prow = w*16+q*4+e, pcol = t*16+lr;
        SP[prow*64 + (((pcol>>3)^(prow&7))<<3) + (pcol&7)] = f2b(p);
      }
    #pragma unroll
    for(int sh=1; sh<16; sh<<=1)
      #pragma unroll
      for(int e=0;e<4;e++) rs[e] += __shfl_xor(rs[e], sh);
    #pragma unroll
    for(int e=0;e<4;e++) l[e] += rs[e];
    int pr = w*16+lr;
    #pragma unroll
    for(int ks=0;ks<2;ks++){
      bf8 pa = *(const bf8*)&SP[pr*64 + (((ks*4+q)^(pr&7))<<3)];
      #pragma unroll
      for(int t2=0;t2<4;t2++){
        int rr = t2*16+lr;
        bf8 vv = *(const bf8*)&SV[cur][rr*64 + (((ks*4+q)^(rr&7))<<3)];
        o[t2] = __builtin_amdgcn_mfma_f32_16x16x32_bf16(pa, vv, o[t2], 0,0,0);
      }
    }
    __syncthreads();
  }
  long pb = (long)(z*17+kc)*256 + jt*64 + w*16;
  #pragma unroll
  for(int e=0;e<4;e++){
    int jg = q*4+e;
    #pragma unroll
    for(int t2=0;t2<4;t2++)
      partO[(pb + jg)*64 + t2*16 + lr] = o[t2][e];
    if(lr==0){ pm[pb + jg] = m[e]; pl[pb + jg] = l[e]; }
  }
}

// merge 17 kc-partials -> avbT16[z][d][j] (bf16, transposed). grid (16 jq, 16 z), 128 thr.
__global__ __launch_bounds__(128)
void k_mrg3(const float* __restrict__ partO, const float* __restrict__ pm,
            const float* __restrict__ pl, u16* __restrict__ avbT16)
{
  int jq = blockIdx.x, z = blockIdx.y, tid = threadIdx.x;
  int j0 = jq*16;
  __shared__ float wk[16][17];
  __shared__ u16 T[16][72];
  if(tid < 16){
    int j = j0 + tid;
    float mm[17];
    float M = -3e38f;
    #pragma unroll
    for(int kc=0;kc<17;kc++){ mm[kc]=pm[(z*17+kc)*256 + j]; M=fmaxf(M,mm[kc]); }
    float s = 0.f;
    #pragma unroll
    for(int kc=0;kc<17;kc++){ float e=expf(mm[kc]-M); wk[tid][kc]=e; s+=e*pl[(z*17+kc)*256 + j]; }
    float inv = 1.f/s;
    #pragma unroll
    for(int kc=0;kc<17;kc++) wk[tid][kc]*=inv;
  }
  __syncthreads();
  float acc[8];
  #pragma unroll
  for(int p=0;p<8;p++) acc[p]=0.f;
  for(int kc=0;kc<17;kc++){
    long base = ((long)(z*17+kc)*256 + j0)*64;
    #pragma unroll
    for(int p=0;p<8;p++){
      int idx = tid + p*128;
      acc[p] += wk[idx>>6][kc]*partO[base + idx];
    }
  }
  #pragma unroll
  for(int p=0;p<8;p++){ int idx = tid + p*128; T[idx>>6][idx&63] = f2b(acc[p]); }
  __syncthreads();
  int d = tid>>1, jh = (tid&1)*8;
  us8 vv;
  #pragma unroll
  for(int u=0;u<8;u++) vv[u] = T[jh+u][d];
  *(us8*)&avbT16[(long)(z*64+d)*256 + j0 + jh] = vv;
}

// ======== fused attn1 + res-conv: S=SCALE*q@kl^T; P=softmax(S); O=P@zav;
// Qo16 = bf16(O + dwconv33(v)). LDS XOR-swizzled; conv phase reuses SKL/SZV. ====
__global__ __launch_bounds__(256)
void k_att1(const u16* __restrict__ qkv16, const u16* __restrict__ kl,
            const u16* __restrict__ zavT, const float* __restrict__ resk,
            u16* __restrict__ Qo16)
{
  int z = blockIdx.y, b = z>>3, h = z&7;
  int m0 = blockIdx.x*64;
  __shared__ u16 SQ[64*64];
  __shared__ u16 SKL[256*64];
  __shared__ u16 SZV[64*256];
  int tid=threadIdx.x, w=tid>>6, lane=tid&63, q=lane>>4, lr=lane&15;
  {
    const u16* qb = qkv16 + (long)b*NP*1536 + h*64;
    #pragma unroll
    for(int p=0;p<2;p++){
      int idx = tid + p*256; int row = idx>>3; int js = ((idx&7)^(row&7))<<3;
      gload_lds(qb + (long)(m0+row)*1536 + js, &SQ[idx*8]);
    }
    const u16* kb = kl + (long)z*16384;
    #pragma unroll
    for(int p=0;p<8;p++){
      int idx = tid + p*256; int row = idx>>3; int js = ((idx&7)^(row&7))<<3;
      gload_lds(kb + row*64 + js, &SKL[idx*8]);
    }
    const u16* zb = zavT + (long)z*16384;
    #pragma unroll
    for(int p=0;p<8;p++){
      int idx = tid + p*256; int row = idx>>5; int cs = ((idx&31)^(row&7))<<3;
      gload_lds(zb + row*256 + cs, &SZV[idx*8]);
    }
  }
  __syncthreads();
  f4 acc[16] = {};
  {
    int ar = w*16+lr;
    bf8 af0 = *(const bf8*)&SQ[ar*64 + ((q^(ar&7))<<3)];
    bf8 af1 = *(const bf8*)&SQ[ar*64 + (((q|4)^(ar&7))<<3)];
    #pragma unroll
    for(int t=0;t<16;t++){
      int br = t*16+lr;
      bf8 b0 = *(const bf8*)&SKL[br*64 + ((q^(br&7))<<3)];
      bf8 b1 = *(const bf8*)&SKL[br*64 + (((q|4)^(br&7))<<3)];
      acc[t] = __builtin_amdgcn_mfma_f32_16x16x32_bf16(af0, b0, acc[t], 0,0,0);
      acc[t] = __builtin_amdgcn_mfma_f32_16x16x32_bf16(af1, b1, acc[t], 0,0,0);
    }
  }
  float mx[4] = {-1e30f,-1e30f,-1e30f,-1e30f};
  #pragma unroll
  for(int t=0;t<16;t++)
    #pragma unroll
    for(int e=0;e<4;e++) mx[e] = fmaxf(mx[e], acc[t][e]*SCALE);
  #pragma unroll
  for(int s=1;s<16;s<<=1)
    #pragma unroll
    for(int e=0;e<4;e++) mx[e] = fmaxf(mx[e], __shfl_xor(mx[e], s));
  float sm[4] = {0.f,0.f,0.f,0.f};
  #pragma unroll
  for(int t=0;t<16;t++)
    #pragma unroll
    for(int e=0;e<4;e++){ float p = expf(acc[t][e]*SCALE - mx[e]); acc[t][e]=p; sm[e]+=p; }
  #pragma unroll
  for(int s=1;s<16;s<<=1)
    #pragma unroll
    for(int e=0;e<4;e++) sm[e] += __shfl_xor(sm[e], s);
  float inv[4];
  #pragma unroll
  for(int e=0;e<4;e++) inv[e] = 1.f/sm[e];
  __syncthreads();
  u16* PS = SKL;   // reuse as 64 rows x 256 cols, swizzled
  #pragma unroll
  for(int t=0;t<16;t++)
    #pragma unroll
    for(int e=0;e<4;e++){
      int prow = w*16 + q*4 + e, pcol = t*16 + lr;
      PS[prow*256 + (((pcol>>3)^(prow&7))<<3) + (pcol&7)] = f2b(acc[t][e]*inv[e]);
    }
  __syncthreads();
  f4 acc2[4] = {};
  int pr = w*16+lr;
  #pragma unroll
  for(int ks=0;ks<8;ks++){
    bf8 af = *(const bf8*)&PS[pr*256 + (((ks*4+q)^(pr&7))<<3)];
    #pragma unroll
    for(int t=0;t<4;t++){
      int rr = t*16+lr;
      bf8 bf_ = *(const bf8*)&SZV[rr*256 + (((ks*4+q)^(rr&7))<<3)];
      acc2[t] = __builtin_amdgcn_mfma_f32_16x16x32_bf16(af, bf_, acc2[t], 0,0,0);
    }
  }
  // ---- fused res-conv epilogue ----
  __syncthreads();                       // all PS/SZV reads done; safe to reuse
  float* PO  = (float*)SZV;              // 64 x 68 fp32
  float* SVW = (float*)SKL;              // 96 x 64 fp32
  #pragma unroll
  for(int t=0;t<4;t++)
    #pragma unroll
    for(int r=0;r<4;r++)
      PO[(w*16 + q*4 + r)*68 + t*16 + lr] = acc2[t][r];
  {
    const u16* vb = qkv16 + (long)b*NP*1536 + 1024 + h*64;
    #pragma unroll
    for(int s=0;s<3;s++){
      int idx = tid + s*256;
      int row = idx>>3, c8 = (idx&7)*8;
      int p = m0 - 16 + row;
      if(p>=0 && p<NP){
        us8 v = *(const us8*)&vb[(long)p*1536 + c8];
        #pragma unroll
        for(int jj=0;jj<8;jj++) SVW[row*64+c8+jj] = b2f(v[jj]);
      } else {
        #pragma unroll
        for(int jj=0;jj<8;jj++) SVW[row*64+c8+jj] = 0.f;
      }
    }
  }
  __syncthreads();
  int d = tid&63, lt = (tid>>6)*16;
  float acc3[16] = {};
  #pragma unroll
  for(int s=0;s<48;s++){
    float val = SVW[(lt+s)*64 + d];
    #pragma unroll
    for(int j=0;j<16;j++){
      int tap = s - j;
      if(tap>=0 && tap<33) acc3[j] += resk[h*33+tap]*val;
    }
  }
  #pragma unroll
  for(int j=0;j<16;j++){
    long idx = ((long)b*NP + m0 + lt + j)*EMB + h*64 + d;
    Qo16[idx] = f2b(PO[(lt+j)*68 + d] + acc3[j]);
  }
}

// weight transpose+convert: in fp32 [K][N] -> out bf16 [N][K]
__global__ void k_wT(const float* __restrict__ in, u16* __restrict__ out, int K, int N){
  int n0=blockIdx.x*32, k0=blockIdx.y*32, tid=threadIdx.x;
  __shared__ float T[32][33];
  int lr=tid&31, lc=tid>>5;
  #pragma unroll
  for(int p=0;p<4;p++) T[lc+8*p][lr] = in[(long)(k0+lc+8*p)*N + n0+lr];
  __syncthreads();
  #pragma unroll
  for(int p=0;p<4;p++) out[(long)(n0+lc+8*p)*K + k0+lr] = f2b(T[lr][lc+8*p]);
}

// merged landmarks + v^T (both read only qkvb16). grid (132, 8, 2), 256 thr.
__global__ __launch_bounds__(256)
void k_lmvt(const u16* __restrict__ qkv16, u16* __restrict__ q_l, u16* __restrict__ k_l,
            u16* __restrict__ vT, float* __restrict__ colsum){
  int h = blockIdx.y, b = blockIdx.z, tid = threadIdx.x;
  __shared__ u16 T[64][72];
  if(blockIdx.x < 64){
    if(blockIdx.y==0 && blockIdx.z==0 && blockIdx.x<16) colsum[blockIdx.x*256 + tid] = 0.f;
    int j = blockIdx.x*4 + (tid>>6), d = tid&63;
    const u16* base = qkv16 + (long)b*NP*1536 + h*64 + d;
    float sq=0.f, sk=0.f;
    for(int l=0;l<17;l++){
      long row = (long)(j*17+l)*1536;
      sq += b2f(base[row]);
      sk += b2f(base[row+512]);
    }
    long o = (((long)b*HEADS + h)*LM + j)*DH + d;
    q_l[o] = f2b(sq * (SCALE/17.0f));
    k_l[o] = f2b(sk * (1.0f/17.0f));
  } else {
    int t0 = (blockIdx.x-64)*64;
    const u16* src = qkv16 + (long)b*NP*1536 + 1024 + h*64;
    for(int s=0;s<2;s++){
      int idx=tid+s*256; int row=idx>>3, c8=(idx&7)*8;
      *(us8*)&T[row][c8] = *(const us8*)&src[(long)(t0+row)*1536 + c8];
    }
    __syncthreads();
    u16* dst = vT + ((long)(b*8+h)*64)*NP;
    int d = tid>>2, j0=(tid&3)*16;
    us8 v0,v1;
    #pragma unroll
    for(int jj=0;jj<8;jj++){ v0[jj]=T[j0+jj][d]; v1[jj]=T[j0+8+jj][d]; }
    *(us8*)&dst[(long)d*NP + t0 + j0]     = v0;
    *(us8*)&dst[(long)d*NP + t0 + j0 + 8] = v1;
  }
}

__global__ void k_cvt16(const float* __restrict__ in, u16* __restrict__ out, long n){
  long i = (long)blockIdx.x*256 + threadIdx.x;
  if(i<n) out[i] = f2b(in[i]);
}

__global__ void k_cls(const float* __restrict__ cls, float* __restrict__ seq){
  int b = blockIdx.x;
  seq[(long)b*NTOK*EMB + threadIdx.x] = cls[threadIdx.x];
}

// LayerNorm of seq into xpb bf16 with 255 zero rows at front
__global__ void k_ln_pad(const float* __restrict__ seq, u16* __restrict__ xp,
                         const float* __restrict__ g, const float* __restrict__ bb){
  int b = blockIdx.y, i = blockIdx.x, tid = threadIdx.x;
  u16* out = xp + ((long)b*NP + i)*EMB;
  if(i < PADF){ out[tid]=0; out[tid+256]=0; return; }
  const float* x = seq + ((long)b*NTOK + (i-PADF))*EMB;
  float v0 = x[tid], v1 = x[tid+256];
  __shared__ float red[256];
  red[tid]=v0+v1; __syncthreads();
  for(int s=128;s>0;s>>=1){ if(tid<s) red[tid]+=red[tid+s]; __syncthreads(); }
  float mu = red[0]*(1.0f/512.0f); __syncthreads();
  float d0=v0-mu, d1=v1-mu;
  red[tid]=d0*d0+d1*d1; __syncthreads();
  for(int s=128;s>0;s>>=1){ if(tid<s) red[tid]+=red[tid+s]; __syncthreads(); }
  float rstd = rsqrtf(red[0]*(1.0f/512.0f) + 1e-5f);
  out[tid]     = f2b(d0*rstd*g[tid]     + bb[tid]);
  out[tid+256] = f2b(d1*rstd*g[tid+256] + bb[tid+256]);
}

// rm == 1 exactly (rows of a softmax sum to 1); cm = max over 16 heads x 256 cols.
__global__ void k_pair_init(const float* __restrict__ att2,
    const float* __restrict__ colsum,
    u16* __restrict__ Xh, u16* __restrict__ Xl,
    u16* __restrict__ Zh, u16* __restrict__ Zl,
    u16* __restrict__ Zth, u16* __restrict__ Ztl)
{
  long zo = (long)blockIdx.z*65536;
  int i0 = blockIdx.y*64, j0 = blockIdx.x*64;
  int tid = threadIdx.x;
  __shared__ float cred[256];
  {
    float cm = 0.f;
    #pragma unroll
    for(int i=0;i<16;i++) cm = fmaxf(cm, colsum[tid + i*256]);
    cred[tid] = cm; __syncthreads();
    for(int s=128;s>0;s>>=1){ if(tid<s) cred[tid]=fmaxf(cred[tid],cred[tid+s]); __syncthreads(); }
  }
  float inv = 1.0f/cred[0];
  __syncthreads();
  __shared__ float T[64][68];
  int li = tid>>2, jc = (tid&3)*16;
  #pragma unroll
  for(int u=0;u<4;u++){
    float4 v = *(const float4*)&att2[zo + (long)(i0+li)*256 + j0 + jc + u*4];
    T[li][jc+u*4]=v.x; T[li][jc+u*4+1]=v.y; T[li][jc+u*4+2]=v.z; T[li][jc+u*4+3]=v.w;
    long o = zo + (long)(i0+li)*256 + j0 + jc + u*4;
    float vv[4] = {v.x,v.y,v.z,v.w};
    us4 xh, xl, zth, ztl;
    #pragma unroll
    for(int c=0;c<4;c++){
      u16 h = f2b(vv[c]); xh[c]=h; xl[c]=f2b(vv[c]-b2f(h));
      float zt = vv[c]*inv;
      u16 h2 = f2b(zt); zth[c]=h2; ztl[c]=f2b(zt-b2f(h2));
    }
    *(us4*)&Xh[o]=xh; *(us4*)&Xl[o]=xl; *(us4*)&Zth[o]=zth; *(us4*)&Ztl[o]=ztl;
  }
  __syncthreads();
  int lj = tid>>2, ic = (tid&3)*16;
  #pragma unroll
  for(int r=0;r<16;r++){
    float x = T[ic+r][lj]*inv;
    u16 h = f2b(x);
    long o = zo + (long)(j0+lj)*256 + i0 + ic + r;
    Zh[o]=h; Zl[o]=f2b(x-b2f(h));
  }
}

// PPEG: 64-ch groups, 4 rows x 64 ch per block, x-split 2; grid (32, 8, 2)
__global__ __launch_bounds__(256)
void k_ppeg(const float* __restrict__ seq, float* __restrict__ out,
    const float* __restrict__ w7,const float* __restrict__ b7,
    const float* __restrict__ w5,const float* __restrict__ b5,
    const float* __restrict__ w3,const float* __restrict__ b3){
  int b = blockIdx.z, cg = blockIdx.y;
  int rp = blockIdx.x>>1, xs = blockIdx.x&1;
  int ch0 = cg*64;
  __shared__ float s7[64*49], s5[64*25], s3[64*9], sbias[64];
  int tid = threadIdx.x;
  for(int i=tid;i<64*49;i+=256) s7[i] = w7[ch0*49+i];
  for(int i=tid;i<64*25;i+=256) s5[i] = w5[ch0*25+i];
  for(int i=tid;i<64*9;i+=256)  s3[i] = w3[ch0*9+i];
  if(tid<64) sbias[tid] = b7[ch0+tid]+b5[ch0+tid]+b3[ch0+tid];
  if(cg==0 && blockIdx.x==0){
    out[(long)b*NTOK*EMB + tid]       = seq[(long)b*NTOK*EMB + tid];
    out[(long)b*NTOK*EMB + 256 + tid] = seq[(long)b*NTOK*EMB + 256 + tid];
  }
  __syncthreads();
  int c = tid & 63;
  int y = rp*4 + (tid>>6);
  const float* sbase = seq + (long)b*NTOK*EMB + EMB + (ch0 + c);
  float* obase = out + (long)b*NTOK*EMB + EMB + (ch0 + c);
  const float* W7 = &s7[c*49];
  const float* W5 = &s5[c*25];
  const float* W3 = &s3[c*9];
  float bsum = sbias[c];
  for(int xc=0;xc<4;xc++){
    int xb = xs*32 + xc*8;
    float acc[8];
    #pragma unroll
    for(int j=0;j<8;j++) acc[j] = sbase[(long)(y*64+xb+j)*EMB] + bsum;
    #pragma unroll
    for(int dy=-3;dy<=3;dy++){
      int yy = y+dy;
      if(yy<0||yy>=64) continue;
      float v[14];
      #pragma unroll
      for(int u=0;u<14;u++){
        int xx = xb + u - 3;
        v[u] = (xx>=0 && xx<64) ? sbase[(long)(yy*64+xx)*EMB] : 0.f;
      }
      #pragma unroll
      for(int dx=-3;dx<=3;dx++){
        float wsum = W7[(dy+3)*7+(dx+3)];
        if(dy>=-2&&dy<=2&&dx>=-2&&dx<=2) wsum += W5[(dy+2)*5+(dx+2)];
        if(dy>=-1&&dy<=1&&dx>=-1&&dx<=1) wsum += W3[(dy+1)*3+(dx+1)];
        #pragma unroll
        for(int j=0;j<8;j++) acc[j] += v[j+dx+3]*wsum;
      }
    }
    #pragma unroll
    for(int j=0;j<8;j++) obase[(long)(y*64+xb+j)*EMB] = acc[j];
  }
}

__global__ void k_final_ln(const float* __restrict__ seq, const float* __restrict__ g,
                           const float* __restrict__ bb, float* __restrict__ out){
  int b = blockIdx.x, tid = threadIdx.x;
  const float* x = seq + (long)b*NTOK*EMB;
  float v0 = x[tid], v1 = x[tid+256];
  __shared__ float red[256];
  red[tid]=v0+v1; __syncthreads();
  for(int s=128;s>0;s>>=1){ if(tid<s) red[tid]+=red[tid+s]; __syncthreads(); }
  float mu = red[0]*(1.0f/512.0f); __syncthreads();
  float d0=v0-mu, d1=v1-mu;
  red[tid]=d0*d0+d1*d1; __syncthreads();
  for(int s=128;s>0;s>>=1){ if(tid<s) red[tid]+=red[tid+s]; __syncthreads(); }
  float rstd = rsqrtf(red[0]*(1.0f/512.0f) + 1e-5f);
  out[b*512+tid]     = d0*rstd*g[tid]     + bb[tid];
  out[b*512+tid+256] = d1*rstd*g[tid+256] + bb[tid+256];
}

// ---------------- host ----------------
extern "C" void kernel_launch(void* const* d_in, const int* in_sizes, int n_in,
                              void* d_out, int out_size, void* d_ws, size_t ws_size,
                              hipStream_t stream) {
  const float* in[24];
  for(int i=0;i<24;i++) in[i] = (const float*)d_in[i];

  float* W = (float*)d_ws;
  size_t off = 0;
  float* seqA = W+off; off += 4195328;        // 2*4097*512
  float* seqB = W+off; off += 4195328;
  float* att2 = W+off; off += 1048576;        // 16*65536
  float* partO= W+off; off += 17825792;       // 16*17*256*64
  float* pm   = W+off; off += 69632;
  float* pl   = W+off; off += 69632;
  u16* xpb    = (u16*)(W+off); off += 2228224;  // 2*4352*512 u16
  u16* qkvb16 = (u16*)(W+off); off += 6684672;  // 2*4352*1536 u16
  u16* vT16   = (u16*)(W+off); off += 2228224;
  u16* q_l16  = (u16*)(W+off); off += 131072;   // 16*256*64 u16
  u16* k_l16  = (u16*)(W+off); off += 131072;
  u16* avbT16 = (u16*)(W+off); off += 131072;
  u16* zavT16 = (u16*)(W+off); off += 131072;
  u16* Qc16   = (u16*)(W+off); off += 2228224;
  u16* qkvwT1 = (u16*)(W+off); off += 393216;   // 1536*512 u16
  u16* qkvwT2 = (u16*)(W+off); off += 393216;
  u16* outwT1 = (u16*)(W+off); off += 131072;   // 512*512 u16
  u16* outwT2 = (u16*)(W+off); off += 131072;
  u16* pairs  = (u16*)(W+off); off += 9437184;  // 18*16*65536 u16
  float* colsum = W+off; off += 4096;           // 16*256
  if (ws_size < off*sizeof(float)) return;

  // h16/wfc1T alias the pairs region (pairs first written at pair_init, after fc1)
  u16* h16   = pairs;
  u16* wfc1T = pairs + 8388608;

  const long PB = 1048576;  // 16*65536
  u16 *Xh=pairs,        *Xl=pairs+PB;
  u16 *Z0h=pairs+2*PB,  *Z0l=pairs+3*PB;
  u16 *Z0th=pairs+4*PB, *Z0tl=pairs+5*PB;
  u16 *Z1h=pairs+6*PB,  *Z1l=pairs+7*PB;
  u16 *P0h=pairs+8*PB,  *P0l=pairs+9*PB;
  u16 *P1h=pairs+10*PB, *P1l=pairs+11*PB;
  u16 *Tth=pairs+12*PB, *Ttl=pairs+13*PB;
  u16 *Uth=pairs+14*PB, *Utl=pairs+15*PB;
  u16 *Vth=pairs+16*PB, *Vtl=pairs+17*PB;

  // weight conversions/transposes
  k_cvt16<<<32768,256,0,stream>>>(in[0], h16, 8388608L);
  k_wT<<<dim3(16,32),256,0,stream>>>(in[1],  wfc1T, 1024, 512);
  k_wT<<<dim3(48,16),256,0,stream>>>(in[6],  qkvwT1, 512, 1536);
  k_wT<<<dim3(48,16),256,0,stream>>>(in[18], qkvwT2, 512, 1536);
  k_wT<<<dim3(16,16),256,0,stream>>>(in[7],  outwT1, 512, 512);
  k_wT<<<dim3(16,16),256,0,stream>>>(in[19], outwT2, 512, 512);

  // fc1 + cls (64x64 tiles -> 1024 blocks = 4/CU)
  k_g64<6><<<dim3(8,64,2),256,0,stream>>>(h16, wfc1T, seqA+EMB, nullptr,
      1024, 1024,1024,512, 4194304L,0, 0,0, (long)NTOK*EMB,0, 1, 1.0f, in[2], 0, 0, 8, 1);
  k_cls<<<2,512,0,stream>>>(in[3], seqA);

  auto attention = [&](float* seq, const float* lng,const float* lnb,
                       const u16* qkvwT, const u16* outwT, const float* outb, const float* resk){
    k_ln_pad<<<dim3(NP,2),256,0,stream>>>(seq, xpb, lng, lnb);
    k_g128<2><<<dim3(12,34,2),256,0,stream>>>(xpb, qkvwT, nullptr, qkvb16,
        512, 512,512,1536, (long)NP*512,0, 0,0, (long)NP*1536,0, 1, 1.0f, nullptr, 0, 0, 12, 1);
    // merged landmarks + vT (+ colsum zero)
    k_lmvt<<<dim3(132,HEADS,2),256,0,stream>>>(qkvb16, q_l16, k_l16, vT16, colsum);
    // fused attn2: scores + row-softmax -> att2 fp32, column sums -> colsum
    k_att2f<<<dim3(4,16),256,0,stream>>>(q_l16, k_l16, att2, colsum);
    // pinv on bf16 pairs, y-recurrence form:
    //   y0 = X@Z0;  per iter: U=15I-y@T, V=13I-y@U, z'=0.25 Z@V, y'=0.25 y@V (fused)
    k_pair_init<<<dim3(4,4,16),256,0,stream>>>(att2, colsum, Xh,Xl, Z0h,Z0l, Z0th,Z0tl);
    dim3 pgrid(4,8,16);
    k_pg3<<<pgrid,256,0,stream>>>(Xh,Xl, Z0th,Z0tl, P0h,P0l,1.0f,0.f, Tth,Ttl,-1.0f,7.f);
    for(int it=0; it<6; it++){
      u16 *Zh_=(it&1)?Z1h:Z0h, *Zl_=(it&1)?Z1l:Z0l;
      u16 *Nh_=(it&1)?Z0h:Z1h, *Nl_=(it&1)?Z0l:Z1l;
      u16 *Pch=(it&1)?P1h:P0h, *Pcl=(it&1)?P1l:P0l;
      u16 *Pnh=(it&1)?P0h:P1h, *Pnl=(it&1)?P0l:P1l;
      k_pg3<<<pgrid,256,0,stream>>>(Pch,Pcl, Tth,Ttl, nullptr,nullptr,0.f,0.f, Uth,Utl,-1.0f,15.f);
      k_pg3<<<pgrid,256,0,stream>>>(Pch,Pcl, Uth,Utl, nullptr,nullptr,0.f,0.f, Vth,Vtl,-1.0f,13.f);
      if(it<5) k_pg3b<<<dim3(4,16,16),256,0,stream>>>(Zh_,Zl_, Pch,Pcl, Vth,Vtl,
                                                      Nh_,Nl_, Pnh,Pnl, Tth,Ttl);
      else     k_pg3<<<pgrid,256,0,stream>>>(Zh_,Zl_, Vth,Vtl, Nh_,Nl_,0.25f,0.f,
                                             nullptr,nullptr,0.f,0.f);
    }
    // fused flash attn3@v: 17 token-chunks x 4 q-tiles x 16 heads, swizzled LDS
    k_att3<<<dim3(17,4,16),256,0,stream>>>(qkvb16, q_l16, vT16, partO, pm, pl);
    k_mrg3<<<dim3(16,16),128,0,stream>>>(partO, pm, pl, avbT16);
    // zavT = avbT @ Z^T  -> bf16
    k_g64<2><<<dim3(4,1,16),256,0,stream>>>(avbT16, Z0h, nullptr, zavT16,
        256, 256,256,256, 0,16384L, 0,65536L, 0,16384L, 16, 1.0f, nullptr, 0, 0, 4, 1);
    // fused attn1 + res-conv: scores + softmax + @zav + dwconv -> Qc16 (bf16)
    k_att1<<<dim3(68,16),256,0,stream>>>(qkvb16, k_l16, zavT16, resk, Qc16);
    // out proj + residual add into seq: 64x64 tiles, no split-K, no atomics.
    k_g64<5><<<dim3(8,65,2),256,0,stream>>>(Qc16, outwT, seq, nullptr,
        512, 512,512,512, (long)NP*512,0, 0,0, (long)NTOK*EMB,0, 1, 1.0f, outb, PADF, 192, 8, 1);
  };

  attention(seqA, in[4], in[5], qkvwT1, outwT1, in[8], in[9]);
  k_ppeg<<<dim3(32,8,2),256,0,stream>>>(seqA, seqB, in[10],in[11],in[12],in[13],in[14],in[15]);
  attention(seqB, in[16], in[17], qkvwT2, outwT2, in[20], in[21]);
  k_final_ln<<<2,256,0,stream>>>(seqB, in[22], in[23], (float*)d_out);
}